// Round 11
// baseline (7740.024 us; speedup 1.0000x reference)
//
#include <hip/hip_runtime.h>
#include <cstdint>

// ---------------------------------------------------------------------------
// ConvGRU-Attention autoencoder, fp32. B=64, T=128, F=64 (1-D k=3 conv over F).
//   * conv split: x-part precomputed (parallel), h-part sequential per batch.
//   * t chunked x4 (TC=32) to bound workspace.
//   * attention: qlen==1 -> fold W_k into query, W_v past softmax (exact).
//   * R11: encoder mega-pipelined too. gru32 stream runs TWO chunks ahead of
//     gru64 so conv_e1(c+1)/conv_e0(c+3) ride as jobs inside the launch
//     carrying gru64(c)+gru32(c+2) (no intra-launch deps; Y0p/A96p/Amp
//     ping-pongs hazard-checked per launch). Decoder = R10-exact.
// ---------------------------------------------------------------------------

#define B_  64
#define T_  128
#define TC  32
#define NCH 4

__device__ __forceinline__ float wsum(float v) {
#pragma unroll
  for (int m = 32; m > 0; m >>= 1) v += __shfl_xor(v, m, 64);
  return v;
}
__device__ __forceinline__ float wmaxr(float v) {
#pragma unroll
  for (int m = 32; m > 0; m >>= 1) v = fmaxf(v, __shfl_xor(v, m, 64));
  return v;
}
__device__ __forceinline__ float sigmoidf_(float x) {
  return 1.f / (1.f + __expf(-x));
}
__device__ __forceinline__ float tanhf_(float x) {
  x = fminf(fmaxf(x, -15.f), 15.f);
  float e2 = __expf(2.f * x);
  return (e2 - 1.f) / (e2 + 1.f);
}

// --------------------------------------------------------------------------
// Fused weight repack: 16 jobs in one launch. grid = (192, 16).
// --------------------------------------------------------------------------
struct PackArgs {
  const float* src[16];
  float* dst[16];
  int intot[16];
  int ic0[16];
  int icn[16];
  int oc[16];
};

__global__ __launch_bounds__(256) void pack_all_kernel(PackArgs pa) {
  const int j = blockIdx.y;
  const int icN = pa.icn[j];
  const int total = pa.oc[j] * icN * 3;
  const int i = blockIdx.x * 256 + threadIdx.x;
  if (i >= total) return;
  const int per_oc = icN * 3;
  const int oc = i / per_oc;
  const int rem = i - oc * per_oc;
  const int ic = rem / 3, dk = rem - ic * 3;
  pa.dst[j][i] =
      pa.src[j][((size_t)(oc * pa.intot[j] + pa.ic0[j] + ic) * 3 + dk) * 3 + 1];
}

// --------------------------------------------------------------------------
// x-part conv body (gates then cand) for one (b,tl) tile. tid in [0,256).
// --------------------------------------------------------------------------
template <int INC, int OG, int OCC>
__device__ __forceinline__ void conv_x_body(
    float (*sin_)[72], int tid, int btl,
    const float* __restrict__ seq, int seqC, size_t sB,
    const float* __restrict__ ctx,
    const float* __restrict__ Wgx, const float* __restrict__ Wcx,
    const float* __restrict__ bg, const float* __restrict__ bc,
    float* __restrict__ out) {
  constexpr int OCT = OG + OCC;
  constexpr int NJ = OG / 32;
  constexpr int NJC = OCC / 32;
  const int b = btl >> 5;
  const int tl = btl & 31;
  const int ocg = tid >> 3;
  const int f0 = (tid & 7) << 3;

  for (int idx = tid; idx < INC * 72; idx += 256) {
    int ic = idx / 72, ff = idx - ic * 72;
    float v = 0.f;
    if (ff >= 1 && ff <= 64) {
      int fs = ff - 1;
      v = (ic < seqC)
              ? seq[(size_t)b * sB + (size_t)tl * seqC * 64 + ic * 64 + fs]
              : ctx[((size_t)b * (INC - seqC) + (ic - seqC)) * 64 + fs];
    }
    sin_[ic][ff] = v;
  }
  __syncthreads();

  if constexpr (INC >= 4) {
    {
      float acc[NJ][8];
#pragma unroll
      for (int j = 0; j < NJ; ++j) {
        float bb = bg[ocg + 32 * j];
#pragma unroll
        for (int ff = 0; ff < 8; ++ff) acc[j][ff] = bb;
      }
      for (int ic0 = 0; ic0 < INC; ic0 += 4) {
        float hv[4][10];
#pragma unroll
        for (int q = 0; q < 4; ++q) {
          float4 a4 = *(const float4*)&sin_[ic0 + q][f0];
          float4 b4 = *(const float4*)&sin_[ic0 + q][f0 + 4];
          float2 c2 = *(const float2*)&sin_[ic0 + q][f0 + 8];
          hv[q][0] = a4.x; hv[q][1] = a4.y; hv[q][2] = a4.z; hv[q][3] = a4.w;
          hv[q][4] = b4.x; hv[q][5] = b4.y; hv[q][6] = b4.z; hv[q][7] = b4.w;
          hv[q][8] = c2.x; hv[q][9] = c2.y;
        }
#pragma unroll
        for (int j = 0; j < NJ; ++j) {
          const int oc = ocg + 32 * j;
          const float4* w4 = (const float4*)(Wgx + ((size_t)oc * INC + ic0) * 3);
          float4 wa = w4[0], wb = w4[1], wc4 = w4[2];
          const float wt[12] = {wa.x, wa.y, wa.z, wa.w, wb.x, wb.y, wb.z, wb.w,
                                wc4.x, wc4.y, wc4.z, wc4.w};
#pragma unroll
          for (int q = 0; q < 4; ++q) {
            const float w0 = wt[3 * q], w1 = wt[3 * q + 1], w2 = wt[3 * q + 2];
#pragma unroll
            for (int ff = 0; ff < 8; ++ff)
              acc[j][ff] = fmaf(w0, hv[q][ff], fmaf(w1, hv[q][ff + 1], fmaf(w2, hv[q][ff + 2], acc[j][ff])));
          }
        }
      }
#pragma unroll
      for (int j = 0; j < NJ; ++j) {
        float* dst = out + ((size_t)btl * OCT + ocg + 32 * j) * 64 + f0;
        *(float4*)dst = make_float4(acc[j][0], acc[j][1], acc[j][2], acc[j][3]);
        *(float4*)(dst + 4) = make_float4(acc[j][4], acc[j][5], acc[j][6], acc[j][7]);
      }
    }
    {
      float acc[NJC][8];
#pragma unroll
      for (int j = 0; j < NJC; ++j) {
        float bb = bc[ocg + 32 * j];
#pragma unroll
        for (int ff = 0; ff < 8; ++ff) acc[j][ff] = bb;
      }
      for (int ic0 = 0; ic0 < INC; ic0 += 4) {
        float hv[4][10];
#pragma unroll
        for (int q = 0; q < 4; ++q) {
          float4 a4 = *(const float4*)&sin_[ic0 + q][f0];
          float4 b4 = *(const float4*)&sin_[ic0 + q][f0 + 4];
          float2 c2 = *(const float2*)&sin_[ic0 + q][f0 + 8];
          hv[q][0] = a4.x; hv[q][1] = a4.y; hv[q][2] = a4.z; hv[q][3] = a4.w;
          hv[q][4] = b4.x; hv[q][5] = b4.y; hv[q][6] = b4.z; hv[q][7] = b4.w;
          hv[q][8] = c2.x; hv[q][9] = c2.y;
        }
#pragma unroll
        for (int j = 0; j < NJC; ++j) {
          const int oc = ocg + 32 * j;
          const float4* w4 = (const float4*)(Wcx + ((size_t)oc * INC + ic0) * 3);
          float4 wa = w4[0], wb = w4[1], wc4 = w4[2];
          const float wt[12] = {wa.x, wa.y, wa.z, wa.w, wb.x, wb.y, wb.z, wb.w,
                                wc4.x, wc4.y, wc4.z, wc4.w};
#pragma unroll
          for (int q = 0; q < 4; ++q) {
            const float w0 = wt[3 * q], w1 = wt[3 * q + 1], w2 = wt[3 * q + 2];
#pragma unroll
            for (int ff = 0; ff < 8; ++ff)
              acc[j][ff] = fmaf(w0, hv[q][ff], fmaf(w1, hv[q][ff + 1], fmaf(w2, hv[q][ff + 2], acc[j][ff])));
          }
        }
      }
#pragma unroll
      for (int j = 0; j < NJC; ++j) {
        float* dst = out + ((size_t)btl * OCT + OG + ocg + 32 * j) * 64 + f0;
        *(float4*)dst = make_float4(acc[j][0], acc[j][1], acc[j][2], acc[j][3]);
        *(float4*)(dst + 4) = make_float4(acc[j][4], acc[j][5], acc[j][6], acc[j][7]);
      }
    }
  } else {
    float hv[10];
    {
      float4 a4 = *(const float4*)&sin_[0][f0];
      float4 b4 = *(const float4*)&sin_[0][f0 + 4];
      float2 c2 = *(const float2*)&sin_[0][f0 + 8];
      hv[0] = a4.x; hv[1] = a4.y; hv[2] = a4.z; hv[3] = a4.w;
      hv[4] = b4.x; hv[5] = b4.y; hv[6] = b4.z; hv[7] = b4.w;
      hv[8] = c2.x; hv[9] = c2.y;
    }
#pragma unroll
    for (int j = 0; j < NJ; ++j) {
      const int oc = ocg + 32 * j;
      const float w0 = Wgx[oc * 3], w1 = Wgx[oc * 3 + 1], w2 = Wgx[oc * 3 + 2];
      float acc[8];
#pragma unroll
      for (int ff = 0; ff < 8; ++ff)
        acc[ff] = fmaf(w0, hv[ff], fmaf(w1, hv[ff + 1], fmaf(w2, hv[ff + 2], bg[oc])));
      float* dst = out + ((size_t)btl * OCT + oc) * 64 + f0;
      *(float4*)dst = make_float4(acc[0], acc[1], acc[2], acc[3]);
      *(float4*)(dst + 4) = make_float4(acc[4], acc[5], acc[6], acc[7]);
    }
#pragma unroll
    for (int j = 0; j < NJC; ++j) {
      const int oc = ocg + 32 * j;
      const float w0 = Wcx[oc * 3], w1 = Wcx[oc * 3 + 1], w2 = Wcx[oc * 3 + 2];
      float acc[8];
#pragma unroll
      for (int ff = 0; ff < 8; ++ff)
        acc[ff] = fmaf(w0, hv[ff], fmaf(w1, hv[ff + 1], fmaf(w2, hv[ff + 2], bc[oc])));
      float* dst = out + ((size_t)btl * OCT + OG + oc) * 64 + f0;
      *(float4*)dst = make_float4(acc[0], acc[1], acc[2], acc[3]);
      *(float4*)(dst + 4) = make_float4(acc[4], acc[5], acc[6], acc[7]);
    }
  }
}

template <int INC, int OG, int OCC>
__global__ __launch_bounds__(256) void conv_x_kernel(
    const float* __restrict__ seq, int seqC, size_t sB,
    const float* __restrict__ ctx,
    const float* __restrict__ Wgx, const float* __restrict__ Wcx,
    const float* __restrict__ bg, const float* __restrict__ bc,
    float* __restrict__ out) {
  __shared__ float sin_[INC][72];
  conv_x_body<INC, OG, OCC>(sin_, threadIdx.x, blockIdx.x, seq, seqC, sB, ctx,
                            Wgx, Wcx, bg, bc, out);
}

// --------------------------------------------------------------------------
// Final 1x1 conv body: one 256-wide tile.
// --------------------------------------------------------------------------
__device__ __forceinline__ void final_body(
    int tid, int tile, const float* __restrict__ z1c,
    const float* __restrict__ wfin, const float* __restrict__ bfin,
    float* __restrict__ out, int tOff) {
  const int idx = tile * 256 + tid;
  const int f = idx & 63;
  const int tl = (idx >> 6) & 31;
  const int b = idx >> 11;
  const float* zp = z1c + ((size_t)b * TC + tl) * 2048 + f;
  float a = bfin[0];
#pragma unroll
  for (int c = 0; c < 32; ++c) a = fmaf(wfin[c], zp[c * 64], a);
  out[(size_t)b * 8192 + (size_t)(tOff + tl) * 64 + f] = a;
}

__global__ __launch_bounds__(256) void final_kernel(
    const float* __restrict__ z1c,
    const float* __restrict__ wfin, const float* __restrict__ bfin,
    float* __restrict__ out, int tOff) {
  final_body(threadIdx.x, blockIdx.x, z1c, wfin, bfin, out, tOff);
}

// --------------------------------------------------------------------------
// GRU recurrence body (R4-exact). 512 threads, NR=HC/32 rows/thread.
// --------------------------------------------------------------------------
template <int HC>
__device__ __forceinline__ void gru_body(
    float* smem,
    const float* __restrict__ A, const float* __restrict__ Wgh,
    const float* __restrict__ Wch, const float* hinit,
    float* __restrict__ Y, size_t yB, float* hfinal, int b) {
  constexpr int NR = HC / 32;
  constexpr int OG = 2 * HC;
  constexpr int OCT = 3 * HC;
  float(*Hs)[68] = (float(*)[68])smem;
  float(*Rs)[68] = (float(*)[68])(smem + HC * 68);
  const int tid = threadIdx.x;
  const int ocg = tid >> 4;
  const int f0 = (tid & 15) << 2;
  const int im = (f0 == 0) ? 0 : f0 - 1;
  const bool lo = (f0 == 0), hi = (f0 == 60);

  float hreg[NR][4];
#pragma unroll
  for (int r = 0; r < NR; ++r) {
    const int oc = ocg + 32 * r;
    const float4 v = *(const float4*)(hinit + ((size_t)b * HC + oc) * 64 + f0);
    hreg[r][0] = v.x; hreg[r][1] = v.y; hreg[r][2] = v.z; hreg[r][3] = v.w;
    *(float4*)&Hs[oc][f0] = v;
  }
  __syncthreads();

  for (int tl = 0; tl < TC; ++tl) {
    const float* Abt = A + ((size_t)b * TC + tl) * (OCT * 64);
    float accr[NR][4], accu[NR][4], accc[NR][4];
#pragma unroll
    for (int r = 0; r < NR; ++r) {
      const int oc = ocg + 32 * r;
      const float4 vr = *(const float4*)(Abt + (size_t)oc * 64 + f0);
      const float4 vu = *(const float4*)(Abt + (size_t)(HC + oc) * 64 + f0);
      const float4 vc = *(const float4*)(Abt + (size_t)(OG + oc) * 64 + f0);
      accr[r][0] = vr.x; accr[r][1] = vr.y; accr[r][2] = vr.z; accr[r][3] = vr.w;
      accu[r][0] = vu.x; accu[r][1] = vu.y; accu[r][2] = vu.z; accu[r][3] = vu.w;
      accc[r][0] = vc.x; accc[r][1] = vc.y; accc[r][2] = vc.z; accc[r][3] = vc.w;
    }
#pragma unroll 2
    for (int hc0 = 0; hc0 < HC; hc0 += 4) {
      float hv[4][6];
#pragma unroll
      for (int q = 0; q < 4; ++q) {
        const float4 h4 = *(const float4*)&Hs[hc0 + q][f0];
        const float lf = Hs[hc0 + q][im];
        const float rt = Hs[hc0 + q][f0 + 4];
        hv[q][0] = lo ? 0.f : lf;
        hv[q][1] = h4.x; hv[q][2] = h4.y; hv[q][3] = h4.z; hv[q][4] = h4.w;
        hv[q][5] = hi ? 0.f : rt;
      }
#pragma unroll
      for (int r = 0; r < NR; ++r) {
        {
          const float4* w4 = (const float4*)(Wgh + ((size_t)(ocg + 32 * r) * HC + hc0) * 3);
          const float4 wa = w4[0], wb = w4[1], wc4 = w4[2];
          const float wt[12] = {wa.x, wa.y, wa.z, wa.w, wb.x, wb.y, wb.z, wb.w,
                                wc4.x, wc4.y, wc4.z, wc4.w};
#pragma unroll
          for (int q = 0; q < 4; ++q) {
            const float w0 = wt[3 * q], w1 = wt[3 * q + 1], w2 = wt[3 * q + 2];
#pragma unroll
            for (int ff = 0; ff < 4; ++ff)
              accr[r][ff] = fmaf(w0, hv[q][ff], fmaf(w1, hv[q][ff + 1], fmaf(w2, hv[q][ff + 2], accr[r][ff])));
          }
        }
        {
          const float4* w4 = (const float4*)(Wgh + ((size_t)(HC + ocg + 32 * r) * HC + hc0) * 3);
          const float4 wa = w4[0], wb = w4[1], wc4 = w4[2];
          const float wt[12] = {wa.x, wa.y, wa.z, wa.w, wb.x, wb.y, wb.z, wb.w,
                                wc4.x, wc4.y, wc4.z, wc4.w};
#pragma unroll
          for (int q = 0; q < 4; ++q) {
            const float w0 = wt[3 * q], w1 = wt[3 * q + 1], w2 = wt[3 * q + 2];
#pragma unroll
            for (int ff = 0; ff < 4; ++ff)
              accu[r][ff] = fmaf(w0, hv[q][ff], fmaf(w1, hv[q][ff + 1], fmaf(w2, hv[q][ff + 2], accu[r][ff])));
          }
        }
      }
    }
    float uu[NR][4];
#pragma unroll
    for (int r = 0; r < NR; ++r) {
      float4 rh;
#pragma unroll
      for (int ff = 0; ff < 4; ++ff) {
        uu[r][ff] = sigmoidf_(accu[r][ff]);
        (&rh.x)[ff] = sigmoidf_(accr[r][ff]) * hreg[r][ff];
      }
      *(float4*)&Rs[ocg + 32 * r][f0] = rh;
    }
    __syncthreads();
#pragma unroll 2
    for (int hc0 = 0; hc0 < HC; hc0 += 4) {
      float hv[4][6];
#pragma unroll
      for (int q = 0; q < 4; ++q) {
        const float4 h4 = *(const float4*)&Rs[hc0 + q][f0];
        const float lf = Rs[hc0 + q][im];
        const float rt = Rs[hc0 + q][f0 + 4];
        hv[q][0] = lo ? 0.f : lf;
        hv[q][1] = h4.x; hv[q][2] = h4.y; hv[q][3] = h4.z; hv[q][4] = h4.w;
        hv[q][5] = hi ? 0.f : rt;
      }
#pragma unroll
      for (int r = 0; r < NR; ++r) {
        const float4* w4 = (const float4*)(Wch + ((size_t)(ocg + 32 * r) * HC + hc0) * 3);
        const float4 wa = w4[0], wb = w4[1], wc4 = w4[2];
        const float wt[12] = {wa.x, wa.y, wa.z, wa.w, wb.x, wb.y, wb.z, wb.w,
                              wc4.x, wc4.y, wc4.z, wc4.w};
#pragma unroll
        for (int q = 0; q < 4; ++q) {
          const float w0 = wt[3 * q], w1 = wt[3 * q + 1], w2 = wt[3 * q + 2];
#pragma unroll
          for (int ff = 0; ff < 4; ++ff)
            accc[r][ff] = fmaf(w0, hv[q][ff], fmaf(w1, hv[q][ff + 1], fmaf(w2, hv[q][ff + 2], accc[r][ff])));
        }
      }
    }
#pragma unroll
    for (int r = 0; r < NR; ++r) {
      const int oc = ocg + 32 * r;
      float4 yv;
#pragma unroll
      for (int ff = 0; ff < 4; ++ff) {
        const float cd = tanhf_(accc[r][ff]);
        const float hn = fmaf(uu[r][ff], cd - hreg[r][ff], hreg[r][ff]);
        hreg[r][ff] = hn;
        (&yv.x)[ff] = hn;
      }
      *(float4*)(Y + (size_t)b * yB + (size_t)tl * (HC * 64) + (size_t)oc * 64 + f0) = yv;
      *(float4*)&Hs[oc][f0] = yv;
    }
    __syncthreads();
  }
#pragma unroll
  for (int r = 0; r < NR; ++r) {
    const int oc = ocg + 32 * r;
    *(float4*)(hfinal + ((size_t)b * HC + oc) * 64 + f0) =
        make_float4(hreg[r][0], hreg[r][1], hreg[r][2], hreg[r][3]);
  }
}

template <int HC>
__global__ __launch_bounds__(512) void gru_rec_kernel(
    const float* __restrict__ A, const float* __restrict__ Wgh,
    const float* __restrict__ Wch, const float* hinit,
    float* __restrict__ Y, size_t yB, float* hfinal) {
  __shared__ float smem[2 * HC * 68];
  gru_body<HC>(smem, A, Wgh, Wch, hinit, Y, yB, hfinal, blockIdx.x);
}

struct GruArgs {
  const float* A;
  const float* Wgh;
  const float* Wch;
  const float* hinit;
  float* Y;
  size_t yB;
  float* hfinal;
};

// R9 heterogeneous gru-only fusion (fallback encoder).
__global__ __launch_bounds__(512) void gru_fused_kernel(GruArgs g64, GruArgs g32) {
  __shared__ float smem[2 * 64 * 68];
  if (blockIdx.x < 64) {
    gru_body<64>(smem, g64.A, g64.Wgh, g64.Wch, g64.hinit, g64.Y, g64.yB,
                 g64.hfinal, blockIdx.x);
  } else {
    gru_body<32>(smem, g32.A, g32.Wgh, g32.Wch, g32.hinit, g32.Y, g32.yB,
                 g32.hfinal, blockIdx.x - 64);
  }
}

// --------------------------------------------------------------------------
// Mega kernel: gru64 blocks + gru32 blocks + conv/final job tiles.
// 512 threads; conv/final jobs run as 2x 256-thread tiles per block.
// kinds: 0 = conv_e0 (INC1), 1 = conv_e1 (INC32), 2 = conv_d0 (INC128),
//        3 = conv_d1 (INC64), 4 = final.
// --------------------------------------------------------------------------
struct ConvJob {
  int kind;
  int nblk;          // 512-thread blocks = tiles/2
  const float* seq;
  int seqC;
  size_t sB;
  const float* ctx;
  const float* w0;
  const float* w1;
  const float* b0;
  const float* b1;
  float* out;
  int tOff;
};

struct MegaArgs {
  GruArgs g64;
  GruArgs g32;
  int ng64, ng32, njobs;
  ConvJob jobs[4];
};

__global__ __launch_bounds__(512) void mega_kernel(MegaArgs ma) {
  __shared__ float smem[18432];  // max(2*64*68 gru, 2*128*72 conv_d0) floats
  int bid = blockIdx.x;
  if (bid < ma.ng64) {
    gru_body<64>(smem, ma.g64.A, ma.g64.Wgh, ma.g64.Wch, ma.g64.hinit,
                 ma.g64.Y, ma.g64.yB, ma.g64.hfinal, bid);
    return;
  }
  bid -= ma.ng64;
  if (bid < ma.ng32) {
    gru_body<32>(smem, ma.g32.A, ma.g32.Wgh, ma.g32.Wch, ma.g32.hinit,
                 ma.g32.Y, ma.g32.yB, ma.g32.hfinal, bid);
    return;
  }
  bid -= ma.ng32;
  const int half = threadIdx.x >> 8;
  const int tid = threadIdx.x & 255;
#pragma unroll 1
  for (int j = 0; j < ma.njobs; ++j) {
    if (bid < ma.jobs[j].nblk) {
      const ConvJob cj = ma.jobs[j];
      const int tile = bid * 2 + half;
      if (cj.kind == 0) {
        conv_x_body<1, 64, 32>((float(*)[72])(smem + half * 1 * 72), tid,
                               tile, cj.seq, cj.seqC, cj.sB, cj.ctx, cj.w0,
                               cj.w1, cj.b0, cj.b1, cj.out);
      } else if (cj.kind == 1) {
        conv_x_body<32, 128, 64>((float(*)[72])(smem + half * 32 * 72), tid,
                                 tile, cj.seq, cj.seqC, cj.sB, cj.ctx, cj.w0,
                                 cj.w1, cj.b0, cj.b1, cj.out);
      } else if (cj.kind == 2) {
        conv_x_body<128, 128, 64>((float(*)[72])(smem + half * 128 * 72), tid,
                                  tile, cj.seq, cj.seqC, cj.sB, cj.ctx, cj.w0,
                                  cj.w1, cj.b0, cj.b1, cj.out);
      } else if (cj.kind == 3) {
        conv_x_body<64, 64, 32>((float(*)[72])(smem + half * 64 * 72), tid,
                                tile, cj.seq, cj.seqC, cj.sB, cj.ctx, cj.w0,
                                cj.w1, cj.b0, cj.b1, cj.out);
      } else {
        final_body(tid, tile, cj.seq, cj.w0, cj.b0, cj.out, cj.tOff);
      }
      return;
    }
    bid -= ma.jobs[j].nblk;
  }
}

// --------------------------------------------------------------------------
// Small fp32 GEMM: O[b][e] = sum_k W[e][k]*X[b][k] + bias[e], M=64.
// --------------------------------------------------------------------------
template <bool WT>
__global__ __launch_bounds__(256) void gemm64_kernel(
    const float* __restrict__ W, int wrs,
    const float* __restrict__ X, int xrs,
    float* __restrict__ O, int ors,
    const float* __restrict__ bias, int K,
    int ebh, size_t hsW, size_t hsX, size_t hsO, size_t hsB) {
  int eb = blockIdx.x;
  if (ebh > 0) {
    int h = blockIdx.x / ebh;
    eb = blockIdx.x - h * ebh;
    W += h * hsW; X += h * hsX; O += h * hsO;
    if (bias) bias += h * hsB;
  }
  const int e0 = eb * 64;
  __shared__ float Xs[64][68];
  __shared__ float Ws[64][68];
  const int tb4 = (threadIdx.x & 15) << 2;
  const int te4 = (threadIdx.x >> 4) << 2;
  float acc[4][4] = {};
  for (int k0 = 0; k0 < K; k0 += 64) {
    {
      const int row = threadIdx.x >> 2;
      const int kq = (threadIdx.x & 3) << 4;
      const float* src = X + (size_t)row * xrs + k0 + kq;
#pragma unroll
      for (int q = 0; q < 4; ++q) {
        float4 v = *(const float4*)(src + (q << 2));
        Xs[kq + (q << 2) + 0][row] = v.x;
        Xs[kq + (q << 2) + 1][row] = v.y;
        Xs[kq + (q << 2) + 2][row] = v.z;
        Xs[kq + (q << 2) + 3][row] = v.w;
      }
    }
    if (!WT) {
      const int row = threadIdx.x >> 2;
      const int kq = (threadIdx.x & 3) << 4;
      const float* src = W + (size_t)(e0 + row) * wrs + k0 + kq;
#pragma unroll
      for (int q = 0; q < 4; ++q) {
        float4 v = *(const float4*)(src + (q << 2));
        Ws[kq + (q << 2) + 0][row] = v.x;
        Ws[kq + (q << 2) + 1][row] = v.y;
        Ws[kq + (q << 2) + 2][row] = v.z;
        Ws[kq + (q << 2) + 3][row] = v.w;
      }
    } else {
      const int row = threadIdx.x >> 2;
      const int eq = (threadIdx.x & 3) << 4;
      const float* src = W + (size_t)(k0 + row) * wrs + e0 + eq;
#pragma unroll
      for (int q = 0; q < 4; ++q)
        *(float4*)&Ws[row][eq + (q << 2)] = *(const float4*)(src + (q << 2));
    }
    __syncthreads();
#pragma unroll 8
    for (int k = 0; k < 64; ++k) {
      float4 xv = *(const float4*)&Xs[k][tb4];
      float4 wv4 = *(const float4*)&Ws[k][te4];
      const float xb[4] = {xv.x, xv.y, xv.z, xv.w};
      const float we[4] = {wv4.x, wv4.y, wv4.z, wv4.w};
#pragma unroll
      for (int i = 0; i < 4; ++i)
#pragma unroll
        for (int j = 0; j < 4; ++j) acc[i][j] = fmaf(xb[i], we[j], acc[i][j]);
    }
    __syncthreads();
  }
#pragma unroll
  for (int i = 0; i < 4; ++i)
#pragma unroll
    for (int j = 0; j < 4; ++j) {
      float v = acc[i][j];
      if (bias) v += bias[e0 + te4 + j];
      O[(size_t)(tb4 + i) * ors + e0 + te4 + j] = v;
    }
}

// --------------------------------------------------------------------------
// Attention, parallel form (qlen==1, folded).
// --------------------------------------------------------------------------
__global__ __launch_bounds__(256) void attn_scores_kernel(
    const float* __restrict__ qkh, const float* __restrict__ mem,
    float* __restrict__ scores) {
  const int b = blockIdx.x >> 4;
  const int tt = blockIdx.x & 15;
  const int h = threadIdx.x >> 6;
  const int lane = threadIdx.x & 63;
  const float4* qk4 = (const float4*)(qkh + ((size_t)b * 4 + h) * 4096);
#pragma unroll 2
  for (int ti = 0; ti < 8; ++ti) {
    const int t = tt * 8 + ti;
    const float4* m4 = (const float4*)(mem + ((size_t)b * 128 + t) * 4096);
    float s = 0.f;
    for (int e = lane; e < 1024; e += 64) {
      float4 q = qk4[e], m = m4[e];
      s = fmaf(q.x, m.x, fmaf(q.y, m.y, fmaf(q.z, m.z, fmaf(q.w, m.w, s))));
    }
    s = wsum(s);
    if (lane == 0) scores[((size_t)b * 4 + h) * 128 + t] = s;
  }
}

__global__ __launch_bounds__(256) void attn_softmax_kernel(
    const float* __restrict__ scores, const float* __restrict__ qbuf,
    const float* __restrict__ bqkv, float* __restrict__ attnp) {
  const int b = blockIdx.x;
  const int h = threadIdx.x >> 6;
  const int lane = threadIdx.x & 63;
  const float4* q4 = (const float4*)(qbuf + (size_t)b * 4096 + h * 1024);
  const float4* k4 = (const float4*)(bqkv + 4096 + h * 1024);
  float qb = 0.f;
#pragma unroll
  for (int d = lane; d < 256; d += 64) {
    float4 q = q4[d], k = k4[d];
    qb = fmaf(q.x, k.x, fmaf(q.y, k.y, fmaf(q.z, k.z, fmaf(q.w, k.w, qb))));
  }
  qb = wsum(qb);
  const float* sc = scores + ((size_t)b * 4 + h) * 128;
  float s0 = (sc[lane] + qb) * 0.03125f;
  float s1 = (sc[lane + 64] + qb) * 0.03125f;
  float mx = wmaxr(fmaxf(s0, s1));
  float e0v = __expf(s0 - mx), e1v = __expf(s1 - mx);
  float inv = 1.f / wsum(e0v + e1v);
  attnp[((size_t)b * 4 + h) * 128 + lane] = e0v * inv;
  attnp[((size_t)b * 4 + h) * 128 + lane + 64] = e1v * inv;
}

__global__ __launch_bounds__(256) void attn_wsum_kernel(
    const float* __restrict__ attnp, const float* __restrict__ mem,
    float* __restrict__ wmem) {
  const int b = blockIdx.x >> 4;
  const int eb = blockIdx.x & 15;
  const int e = eb * 256 + threadIdx.x;
  __shared__ float ap[4][128];
  for (int i = threadIdx.x; i < 512; i += 256)
    ap[i >> 7][i & 127] = attnp[(size_t)b * 512 + i];
  __syncthreads();
  float a0 = 0, a1 = 0, a2 = 0, a3 = 0;
  const float* mb = mem + (size_t)b * 128 * 4096 + e;
#pragma unroll 4
  for (int t = 0; t < 128; ++t) {
    float m = mb[(size_t)t * 4096];
    a0 = fmaf(ap[0][t], m, a0);
    a1 = fmaf(ap[1][t], m, a1);
    a2 = fmaf(ap[2][t], m, a2);
    a3 = fmaf(ap[3][t], m, a3);
  }
  wmem[((size_t)b * 4 + 0) * 4096 + e] = a0;
  wmem[((size_t)b * 4 + 1) * 4096 + e] = a1;
  wmem[((size_t)b * 4 + 2) * 4096 + e] = a2;
  wmem[((size_t)b * 4 + 3) * 4096 + e] = a3;
}

// ==========================================================================
extern "C" void kernel_launch(void* const* d_in, const int* in_sizes, int n_in,
                              void* d_out, int out_size, void* d_ws, size_t ws_size,
                              hipStream_t stream) {
  (void)in_sizes; (void)n_in; (void)out_size;
  const float* x     = (const float*)d_in[0];
  const float* wg_e0 = (const float*)d_in[1];
  const float* bg_e0 = (const float*)d_in[2];
  const float* wc_e0 = (const float*)d_in[3];
  const float* bc_e0 = (const float*)d_in[4];
  const float* wg_e1 = (const float*)d_in[5];
  const float* bg_e1 = (const float*)d_in[6];
  const float* wc_e1 = (const float*)d_in[7];
  const float* bc_e1 = (const float*)d_in[8];
  const float* wg_d0 = (const float*)d_in[9];
  const float* bg_d0 = (const float*)d_in[10];
  const float* wc_d0 = (const float*)d_in[11];
  const float* bc_d0 = (const float*)d_in[12];
  const float* wg_d1 = (const float*)d_in[13];
  const float* bg_d1 = (const float*)d_in[14];
  const float* wc_d1 = (const float*)d_in[15];
  const float* bc_d1 = (const float*)d_in[16];
  const float* w_qkv = (const float*)d_in[17];
  const float* b_qkv = (const float*)d_in[18];
  const float* w_out = (const float*)d_in[19];
  const float* b_out = (const float*)d_in[20];
  const float* w_fin = (const float*)d_in[21];
  const float* b_fin = (const float*)d_in[22];
  float* out = (float*)d_out;

  float* WS = (float*)d_ws;
  size_t off = 0;
  auto alloc = [&](size_t n) { float* p = WS + off; off += (n + 63) & ~(size_t)63; return p; };
  float* Amp0 = alloc((size_t)B_ * TC * 192 * 64);
  float* A960 = alloc((size_t)B_ * TC * 96 * 64);
  float* Y0p0 = alloc((size_t)B_ * TC * 32 * 64);
  float* Y1   = alloc((size_t)B_ * T_ * 64 * 64);
  float* Z0p[2] = {alloc((size_t)B_ * TC * 64 * 64), alloc((size_t)B_ * TC * 64 * 64)};
  float* Z1p0 = alloc((size_t)B_ * TC * 32 * 64);
  float* He0p[2] = {alloc((size_t)B_ * 32 * 64), alloc((size_t)B_ * 32 * 64)};
  float* He1p[2] = {alloc((size_t)B_ * 64 * 64), alloc((size_t)B_ * 64 * 64)};
  float* Hd0p[2] = {alloc((size_t)B_ * 64 * 64), alloc((size_t)B_ * 64 * 64)};
  float* Hd1p[2] = {alloc((size_t)B_ * 32 * 64), alloc((size_t)B_ * 32 * 64)};
  float* QBUF = alloc((size_t)B_ * 4096);
  float* QKH  = alloc((size_t)B_ * 4 * 4096);
  float* WMEM = alloc((size_t)B_ * 4 * 4096);
  float* CTXB = alloc((size_t)B_ * 4096);
  float* CTXO = alloc((size_t)B_ * 4096);
  float* SCR  = alloc((size_t)B_ * 4 * 128);
  float* ATTN = alloc((size_t)B_ * 4 * 128);
  float* wgx_e0 = alloc(64 * 1 * 3);    float* wgh_e0 = alloc(64 * 32 * 3);
  float* wcx_e0 = alloc(32 * 1 * 3);    float* wch_e0 = alloc(32 * 32 * 3);
  float* wgx_e1 = alloc(128 * 32 * 3);  float* wgh_e1 = alloc(128 * 64 * 3);
  float* wcx_e1 = alloc(64 * 32 * 3);   float* wch_e1 = alloc(64 * 64 * 3);
  float* wgx_d0 = alloc(128 * 128 * 3); float* wgh_d0 = alloc(128 * 64 * 3);
  float* wcx_d0 = alloc(64 * 128 * 3);  float* wch_d0 = alloc(64 * 64 * 3);
  float* wgx_d1 = alloc(64 * 64 * 3);   float* wgh_d1 = alloc(64 * 32 * 3);
  float* wcx_d1 = alloc(32 * 64 * 3);   float* wch_d1 = alloc(32 * 32 * 3);
  const size_t off_r9 = off;
  float* Amp1 = alloc((size_t)B_ * TC * 192 * 64);
  float* A961 = alloc((size_t)B_ * TC * 96 * 64);
  float* Z1p1 = alloc((size_t)B_ * TC * 32 * 64);
  float* Y0p1 = alloc((size_t)B_ * TC * 32 * 64);
  const size_t off_full = off;
  if (ws_size < off_r9 * sizeof(float)) return;
  const bool mega_ok = (ws_size >= off_full * sizeof(float));

  float* Amp[2] = {Amp0, Amp1};
  float* A96p[2] = {A960, A961};
  float* Z1p[2] = {Z1p0, Z1p1};
  float* Y0p[2] = {Y0p0, Y0p1};

  // Fused weight repack (16 jobs, one launch).
  {
    PackArgs pa;
    const float* srcs[16] = {wg_e0, wg_e0, wc_e0, wc_e0, wg_e1, wg_e1, wc_e1, wc_e1,
                             wg_d0, wg_d0, wc_d0, wc_d0, wg_d1, wg_d1, wc_d1, wc_d1};
    float* dsts[16] = {wgx_e0, wgh_e0, wcx_e0, wch_e0, wgx_e1, wgh_e1, wcx_e1, wch_e1,
                       wgx_d0, wgh_d0, wcx_d0, wch_d0, wgx_d1, wgh_d1, wcx_d1, wch_d1};
    int intot[16] = {33, 33, 33, 33, 96, 96, 96, 96, 192, 192, 192, 192, 96, 96, 96, 96};
    int ic0[16]   = {0, 1, 0, 1, 0, 32, 0, 32, 0, 128, 0, 128, 0, 64, 0, 64};
    int icn[16]   = {1, 32, 1, 32, 32, 64, 32, 64, 128, 64, 128, 64, 64, 32, 64, 32};
    int occ[16]   = {64, 64, 32, 32, 128, 128, 64, 64, 128, 128, 64, 64, 64, 64, 32, 32};
    for (int j = 0; j < 16; ++j) {
      pa.src[j] = srcs[j]; pa.dst[j] = dsts[j];
      pa.intot[j] = intot[j]; pa.ic0[j] = ic0[j]; pa.icn[j] = icn[j]; pa.oc[j] = occ[j];
    }
    pack_all_kernel<<<dim3(192, 16), 256, 0, stream>>>(pa);
  }

  hipMemsetAsync(He0p[0], 0, (size_t)B_ * 32 * 64 * 4, stream);
  hipMemsetAsync(He1p[0], 0, (size_t)B_ * 64 * 64 * 4, stream);

  // --- mega helpers ---
  auto mega = [&](const GruArgs* a64, const GruArgs* a32, int nj,
                  const ConvJob* js) {
    MegaArgs ma{};
    ma.ng64 = a64 ? 64 : 0; if (a64) ma.g64 = *a64;
    ma.ng32 = a32 ? 64 : 0; if (a32) ma.g32 = *a32;
    ma.njobs = nj;
    int grid = ma.ng64 + ma.ng32;
    for (int i = 0; i < nj; ++i) { ma.jobs[i] = js[i]; grid += js[i].nblk; }
    mega_kernel<<<grid, 512, 0, stream>>>(ma);
  };
  auto JE0 = [&](int c, float* dst) {
    ConvJob j{}; j.kind = 0; j.nblk = 1024;
    j.seq = x + (size_t)c * TC * 64; j.seqC = 1; j.sB = (size_t)T_ * 64;
    j.ctx = nullptr; j.w0 = wgx_e0; j.w1 = wcx_e0; j.b0 = bg_e0; j.b1 = bc_e0;
    j.out = dst; return j;
  };
  auto JE1 = [&](float* y0src, float* dst) {
    ConvJob j{}; j.kind = 1; j.nblk = 1024;
    j.seq = y0src; j.seqC = 32; j.sB = (size_t)TC * 2048;
    j.ctx = nullptr; j.w0 = wgx_e1; j.w1 = wcx_e1; j.b0 = bg_e1; j.b1 = bc_e1;
    j.out = dst; return j;
  };
  auto JD0 = [&](int c, float* dst) {
    ConvJob j{}; j.kind = 2; j.nblk = 1024;
    j.seq = Y1 + (size_t)c * TC * 4096; j.seqC = 64; j.sB = (size_t)T_ * 4096;
    j.ctx = CTXO; j.w0 = wgx_d0; j.w1 = wcx_d0; j.b0 = bg_d0; j.b1 = bc_d0;
    j.out = dst; return j;
  };
  auto JD1 = [&](float* z0src, float* dst) {
    ConvJob j{}; j.kind = 3; j.nblk = 1024;
    j.seq = z0src; j.seqC = 64; j.sB = (size_t)TC * 4096;
    j.ctx = nullptr; j.w0 = wgx_d1; j.w1 = wcx_d1; j.b0 = bg_d1; j.b1 = bc_d1;
    j.out = dst; return j;
  };
  auto JFIN = [&](float* z1src, int tOff) {
    ConvJob j{}; j.kind = 4; j.nblk = 256;
    j.seq = z1src; j.w0 = w_fin; j.b0 = b_fin; j.out = out; j.tOff = tOff;
    return j;
  };

  // -------- encoder --------
  if (mega_ok) {
    // gru32 runs 2 chunks ahead of gru64; conv_e1(c+1)/conv_e0(c+3) are jobs.
    GruArgs ge32[4], ge64[4];
    for (int c = 0; c < 4; ++c) {
      ge32[c] = {A96p[c & 1], wgh_e0, wch_e0, He0p[c & 1],
                 Y0p[c & 1], (size_t)TC * 2048, He0p[(c + 1) & 1]};
      ge64[c] = {Amp[c & 1], wgh_e1, wch_e1, He1p[c & 1],
                 Y1 + (size_t)c * TC * 4096, (size_t)T_ * 4096, He1p[(c + 1) & 1]};
    }
    // L0: conv_e0(0), conv_e0(1)
    { ConvJob js[2] = {JE0(0, A96p[0]), JE0(1, A96p[1])};
      mega(nullptr, nullptr, 2, js); }
    // L1: gru32(0)
    gru_rec_kernel<32><<<64, 512, 0, stream>>>(
        A96p[0], wgh_e0, wch_e0, He0p[0], Y0p[0], (size_t)TC * 2048, He0p[1]);
    // L2: gru32(1) + {conv_e1(0)->Amp0, conv_e0(2)->A96p0}
    { ConvJob js[2] = {JE1(Y0p[0], Amp[0]), JE0(2, A96p[0])};
      mega(nullptr, &ge32[1], 2, js); }
    // L3: gru64(0) + gru32(2) + {conv_e1(1)->Amp1, conv_e0(3)->A96p1}
    { ConvJob js[2] = {JE1(Y0p[1], Amp[1]), JE0(3, A96p[1])};
      mega(&ge64[0], &ge32[2], 2, js); }
    // L4: gru64(1) + gru32(3) + {conv_e1(2)->Amp0}
    { ConvJob js[1] = {JE1(Y0p[0], Amp[0])};
      mega(&ge64[1], &ge32[3], 1, js); }
    // L5: gru64(2) + {conv_e1(3)->Amp1}
    { ConvJob js[1] = {JE1(Y0p[1], Amp[1])};
      mega(&ge64[2], nullptr, 1, js); }
    // L6: gru64(3)
    gru_rec_kernel<64><<<64, 512, 0, stream>>>(
        Amp[1], wgh_e1, wch_e1, He1p[1], Y1 + (size_t)3 * TC * 4096,
        (size_t)T_ * 4096, He1p[0]);
  } else {
    // Fallback: R9 encoder (single Y0 buffer).
    auto conv_e0 = [&](int c) {
      conv_x_kernel<1, 64, 32><<<2048, 256, 0, stream>>>(
          x + (size_t)c * TC * 64, 1, (size_t)T_ * 64, nullptr,
          wgx_e0, wcx_e0, bg_e0, bc_e0, A96p[0]);
    };
    auto conv_e1 = [&]() {
      conv_x_kernel<32, 128, 64><<<2048, 256, 0, stream>>>(
          Y0p[0], 32, (size_t)TC * 2048, nullptr,
          wgx_e1, wcx_e1, bg_e1, bc_e1, Amp[0]);
    };
    conv_e0(0);
    gru_rec_kernel<32><<<64, 512, 0, stream>>>(
        A96p[0], wgh_e0, wch_e0, He0p[0], Y0p[0], (size_t)TC * 2048, He0p[1]);
    conv_e1();
    for (int c = 0; c < NCH; ++c) {
      GruArgs g64 = {Amp[0], wgh_e1, wch_e1, He1p[c & 1],
                     Y1 + (size_t)c * TC * 4096, (size_t)T_ * 4096, He1p[(c + 1) & 1]};
      if (c < NCH - 1) {
        conv_e0(c + 1);
        GruArgs g32 = {A96p[0], wgh_e0, wch_e0, He0p[(c + 1) & 1],
                       Y0p[0], (size_t)TC * 2048, He0p[c & 1]};
        gru_fused_kernel<<<128, 512, 0, stream>>>(g64, g32);
        conv_e1();
      } else {
        gru_rec_kernel<64><<<64, 512, 0, stream>>>(
            g64.A, g64.Wgh, g64.Wch, g64.hinit, g64.Y, g64.yB, g64.hfinal);
      }
    }
  }
  float* He0f = He0p[0];
  float* He1f = He1p[0];

  // -------- attention (query len 1, folded) --------
  const float* wq = w_qkv;
  const float* wk = w_qkv + (size_t)4096 * 4096;
  const float* wv = w_qkv + (size_t)8192 * 4096;
  gemm64_kernel<false><<<64, 256, 0, stream>>>(wq, 4096, He1f, 4096, QBUF, 4096,
                                               b_qkv, 4096, 0, 0, 0, 0, 0);
  gemm64_kernel<true><<<256, 256, 0, stream>>>(wk, 4096, QBUF, 4096, QKH, 16384,
                                               nullptr, 1024, 64,
                                               (size_t)1024 * 4096, 1024, 4096, 0);
  attn_scores_kernel<<<B_ * 16, 256, 0, stream>>>(QKH, Y1, SCR);
  attn_softmax_kernel<<<B_, 256, 0, stream>>>(SCR, QBUF, b_qkv, ATTN);
  attn_wsum_kernel<<<B_ * 16, 256, 0, stream>>>(ATTN, Y1, WMEM);
  gemm64_kernel<false><<<64, 256, 0, stream>>>(wv, 4096, WMEM, 16384, CTXB, 4096,
                                               b_qkv + 8192, 4096, 16,
                                               (size_t)1024 * 4096, 4096, 1024, 1024);
  gemm64_kernel<false><<<64, 256, 0, stream>>>(w_out, 4096, CTXB, 4096, CTXO, 4096,
                                               b_out, 4096, 0, 0, 0, 0, 0);

  // -------- decoder (R10-exact mega schedule) --------
  if (mega_ok) {
    GruArgs gd0[4], gd1[4];
    for (int c = 0; c < 4; ++c) {
      gd0[c] = {Amp[c & 1], wgh_d0, wch_d0,
                (c == 0 ? He1f : Hd0p[c & 1]),
                Z0p[c & 1], (size_t)TC * 4096, Hd0p[(c + 1) & 1]};
      gd1[c] = {A96p[c & 1], wgh_d1, wch_d1,
                (c == 0 ? He0f : Hd1p[c & 1]),
                Z1p[c & 1], (size_t)TC * 2048, Hd1p[(c + 1) & 1]};
    }
    conv_x_kernel<128, 128, 64><<<2048, 256, 0, stream>>>(
        Y1, 64, (size_t)T_ * 4096, CTXO, wgx_d0, wcx_d0, bg_d0, bc_d0, Amp[0]);
    { ConvJob js[1] = {JD0(1, Amp[1])};
      mega(&gd0[0], nullptr, 1, js); }
    { ConvJob js[2] = {JD1(Z0p[0], A96p[0]), JD0(2, Amp[0])};
      mega(&gd0[1], nullptr, 2, js); }
    { ConvJob js[2] = {JD1(Z0p[1], A96p[1]), JD0(3, Amp[1])};
      mega(&gd0[2], &gd1[0], 2, js); }
    { ConvJob js[2] = {JD1(Z0p[0], A96p[0]), JFIN(Z1p[0], 0)};
      mega(&gd0[3], &gd1[1], 2, js); }
    { ConvJob js[2] = {JD1(Z0p[1], A96p[1]), JFIN(Z1p[1], TC)};
      mega(nullptr, &gd1[2], 2, js); }
    { ConvJob js[1] = {JFIN(Z1p[0], 2 * TC)};
      mega(nullptr, &gd1[3], 1, js); }
    final_kernel<<<512, 256, 0, stream>>>(Z1p[1], w_fin, b_fin, out, 3 * TC);
  } else {
    auto conv_d0 = [&](int c) {
      conv_x_kernel<128, 128, 64><<<2048, 256, 0, stream>>>(
          Y1 + (size_t)c * TC * 4096, 64, (size_t)T_ * 4096, CTXO,
          wgx_d0, wcx_d0, bg_d0, bc_d0, Amp[0]);
    };
    auto conv_d1 = [&](int c) {
      conv_x_kernel<64, 64, 32><<<2048, 256, 0, stream>>>(
          Z0p[c & 1], 64, (size_t)TC * 4096, nullptr,
          wgx_d1, wcx_d1, bg_d1, bc_d1, A96p[0]);
    };
    conv_d0(0);
    gru_rec_kernel<64><<<64, 512, 0, stream>>>(
        Amp[0], wgh_d0, wch_d0, He1f, Z0p[0], (size_t)TC * 4096, Hd0p[1]);
    conv_d1(0);
    for (int c = 1; c < NCH; ++c) {
      conv_d0(c);
      GruArgs g64 = {Amp[0], wgh_d0, wch_d0, Hd0p[c & 1],
                     Z0p[c & 1], (size_t)TC * 4096, Hd0p[(c + 1) & 1]};
      GruArgs g32 = {A96p[0], wgh_d1, wch_d1,
                     (c - 1 == 0 ? He0f : Hd1p[(c - 1) & 1]),
                     Z1p[0], (size_t)TC * 2048, Hd1p[c & 1]};
      gru_fused_kernel<<<128, 512, 0, stream>>>(g64, g32);
      final_kernel<<<512, 256, 0, stream>>>(Z1p[0], w_fin, b_fin, out, (c - 1) * TC);
      conv_d1(c);
    }
    gru_rec_kernel<32><<<64, 512, 0, stream>>>(
        A96p[0], wgh_d1, wch_d1, Hd1p[1], Z1p[0], (size_t)TC * 2048, Hd1p[0]);
    final_kernel<<<512, 256, 0, stream>>>(Z1p[0], w_fin, b_fin, out, 3 * TC);
  }
}

// Round 13
// 7724.506 us; speedup vs baseline: 1.0020x; 1.0020x over previous
//
#include <hip/hip_runtime.h>
#include <cstdint>

// ---------------------------------------------------------------------------
// ConvGRU-Attention autoencoder, fp32. B=64, T=128, F=64 (1-D k=3 conv over F).
//   * conv split: x-part precomputed (parallel), h-part sequential per batch.
//   * t chunked x4 (TC=32) to bound workspace.
//   * attention: qlen==1 -> fold W_k into query, W_v past softmax (exact).
//   * R13: R10-exact structure (validated at 7.72 ms) + s_setprio(1) around
//     the gru main loop so critical-path gru waves win issue arbitration over
//     co-resident conv-job waves in mega launches. (R12's extra template
//     instantiation in mega_kernel crashed the compiler; reverted.)
// ---------------------------------------------------------------------------

#define B_  64
#define T_  128
#define TC  32
#define NCH 4

__device__ __forceinline__ float wsum(float v) {
#pragma unroll
  for (int m = 32; m > 0; m >>= 1) v += __shfl_xor(v, m, 64);
  return v;
}
__device__ __forceinline__ float wmaxr(float v) {
#pragma unroll
  for (int m = 32; m > 0; m >>= 1) v = fmaxf(v, __shfl_xor(v, m, 64));
  return v;
}
__device__ __forceinline__ float sigmoidf_(float x) {
  return 1.f / (1.f + __expf(-x));
}
__device__ __forceinline__ float tanhf_(float x) {
  x = fminf(fmaxf(x, -15.f), 15.f);
  float e2 = __expf(2.f * x);
  return (e2 - 1.f) / (e2 + 1.f);
}

// --------------------------------------------------------------------------
// Fused weight repack: 16 jobs in one launch. grid = (192, 16).
// --------------------------------------------------------------------------
struct PackArgs {
  const float* src[16];
  float* dst[16];
  int intot[16];
  int ic0[16];
  int icn[16];
  int oc[16];
};

__global__ __launch_bounds__(256) void pack_all_kernel(PackArgs pa) {
  const int j = blockIdx.y;
  const int icN = pa.icn[j];
  const int total = pa.oc[j] * icN * 3;
  const int i = blockIdx.x * 256 + threadIdx.x;
  if (i >= total) return;
  const int per_oc = icN * 3;
  const int oc = i / per_oc;
  const int rem = i - oc * per_oc;
  const int ic = rem / 3, dk = rem - ic * 3;
  pa.dst[j][i] =
      pa.src[j][((size_t)(oc * pa.intot[j] + pa.ic0[j] + ic) * 3 + dk) * 3 + 1];
}

// --------------------------------------------------------------------------
// x-part conv body (gates then cand) for one (b,tl) tile. tid in [0,256).
// --------------------------------------------------------------------------
template <int INC, int OG, int OCC>
__device__ __forceinline__ void conv_x_body(
    float (*sin_)[72], int tid, int btl,
    const float* __restrict__ seq, int seqC, size_t sB,
    const float* __restrict__ ctx,
    const float* __restrict__ Wgx, const float* __restrict__ Wcx,
    const float* __restrict__ bg, const float* __restrict__ bc,
    float* __restrict__ out) {
  constexpr int OCT = OG + OCC;
  constexpr int NJ = OG / 32;
  constexpr int NJC = OCC / 32;
  const int b = btl >> 5;
  const int tl = btl & 31;
  const int ocg = tid >> 3;
  const int f0 = (tid & 7) << 3;

  for (int idx = tid; idx < INC * 72; idx += 256) {
    int ic = idx / 72, ff = idx - ic * 72;
    float v = 0.f;
    if (ff >= 1 && ff <= 64) {
      int fs = ff - 1;
      v = (ic < seqC)
              ? seq[(size_t)b * sB + (size_t)tl * seqC * 64 + ic * 64 + fs]
              : ctx[((size_t)b * (INC - seqC) + (ic - seqC)) * 64 + fs];
    }
    sin_[ic][ff] = v;
  }
  __syncthreads();

  if constexpr (INC >= 4) {
    {
      float acc[NJ][8];
#pragma unroll
      for (int j = 0; j < NJ; ++j) {
        float bb = bg[ocg + 32 * j];
#pragma unroll
        for (int ff = 0; ff < 8; ++ff) acc[j][ff] = bb;
      }
      for (int ic0 = 0; ic0 < INC; ic0 += 4) {
        float hv[4][10];
#pragma unroll
        for (int q = 0; q < 4; ++q) {
          float4 a4 = *(const float4*)&sin_[ic0 + q][f0];
          float4 b4 = *(const float4*)&sin_[ic0 + q][f0 + 4];
          float2 c2 = *(const float2*)&sin_[ic0 + q][f0 + 8];
          hv[q][0] = a4.x; hv[q][1] = a4.y; hv[q][2] = a4.z; hv[q][3] = a4.w;
          hv[q][4] = b4.x; hv[q][5] = b4.y; hv[q][6] = b4.z; hv[q][7] = b4.w;
          hv[q][8] = c2.x; hv[q][9] = c2.y;
        }
#pragma unroll
        for (int j = 0; j < NJ; ++j) {
          const int oc = ocg + 32 * j;
          const float4* w4 = (const float4*)(Wgx + ((size_t)oc * INC + ic0) * 3);
          float4 wa = w4[0], wb = w4[1], wc4 = w4[2];
          const float wt[12] = {wa.x, wa.y, wa.z, wa.w, wb.x, wb.y, wb.z, wb.w,
                                wc4.x, wc4.y, wc4.z, wc4.w};
#pragma unroll
          for (int q = 0; q < 4; ++q) {
            const float w0 = wt[3 * q], w1 = wt[3 * q + 1], w2 = wt[3 * q + 2];
#pragma unroll
            for (int ff = 0; ff < 8; ++ff)
              acc[j][ff] = fmaf(w0, hv[q][ff], fmaf(w1, hv[q][ff + 1], fmaf(w2, hv[q][ff + 2], acc[j][ff])));
          }
        }
      }
#pragma unroll
      for (int j = 0; j < NJ; ++j) {
        float* dst = out + ((size_t)btl * OCT + ocg + 32 * j) * 64 + f0;
        *(float4*)dst = make_float4(acc[j][0], acc[j][1], acc[j][2], acc[j][3]);
        *(float4*)(dst + 4) = make_float4(acc[j][4], acc[j][5], acc[j][6], acc[j][7]);
      }
    }
    {
      float acc[NJC][8];
#pragma unroll
      for (int j = 0; j < NJC; ++j) {
        float bb = bc[ocg + 32 * j];
#pragma unroll
        for (int ff = 0; ff < 8; ++ff) acc[j][ff] = bb;
      }
      for (int ic0 = 0; ic0 < INC; ic0 += 4) {
        float hv[4][10];
#pragma unroll
        for (int q = 0; q < 4; ++q) {
          float4 a4 = *(const float4*)&sin_[ic0 + q][f0];
          float4 b4 = *(const float4*)&sin_[ic0 + q][f0 + 4];
          float2 c2 = *(const float2*)&sin_[ic0 + q][f0 + 8];
          hv[q][0] = a4.x; hv[q][1] = a4.y; hv[q][2] = a4.z; hv[q][3] = a4.w;
          hv[q][4] = b4.x; hv[q][5] = b4.y; hv[q][6] = b4.z; hv[q][7] = b4.w;
          hv[q][8] = c2.x; hv[q][9] = c2.y;
        }
#pragma unroll
        for (int j = 0; j < NJC; ++j) {
          const int oc = ocg + 32 * j;
          const float4* w4 = (const float4*)(Wcx + ((size_t)oc * INC + ic0) * 3);
          float4 wa = w4[0], wb = w4[1], wc4 = w4[2];
          const float wt[12] = {wa.x, wa.y, wa.z, wa.w, wb.x, wb.y, wb.z, wb.w,
                                wc4.x, wc4.y, wc4.z, wc4.w};
#pragma unroll
          for (int q = 0; q < 4; ++q) {
            const float w0 = wt[3 * q], w1 = wt[3 * q + 1], w2 = wt[3 * q + 2];
#pragma unroll
            for (int ff = 0; ff < 8; ++ff)
              acc[j][ff] = fmaf(w0, hv[q][ff], fmaf(w1, hv[q][ff + 1], fmaf(w2, hv[q][ff + 2], acc[j][ff])));
          }
        }
      }
#pragma unroll
      for (int j = 0; j < NJC; ++j) {
        float* dst = out + ((size_t)btl * OCT + OG + ocg + 32 * j) * 64 + f0;
        *(float4*)dst = make_float4(acc[j][0], acc[j][1], acc[j][2], acc[j][3]);
        *(float4*)(dst + 4) = make_float4(acc[j][4], acc[j][5], acc[j][6], acc[j][7]);
      }
    }
  } else {
    float hv[10];
    {
      float4 a4 = *(const float4*)&sin_[0][f0];
      float4 b4 = *(const float4*)&sin_[0][f0 + 4];
      float2 c2 = *(const float2*)&sin_[0][f0 + 8];
      hv[0] = a4.x; hv[1] = a4.y; hv[2] = a4.z; hv[3] = a4.w;
      hv[4] = b4.x; hv[5] = b4.y; hv[6] = b4.z; hv[7] = b4.w;
      hv[8] = c2.x; hv[9] = c2.y;
    }
#pragma unroll
    for (int j = 0; j < NJ; ++j) {
      const int oc = ocg + 32 * j;
      const float w0 = Wgx[oc * 3], w1 = Wgx[oc * 3 + 1], w2 = Wgx[oc * 3 + 2];
      float acc[8];
#pragma unroll
      for (int ff = 0; ff < 8; ++ff)
        acc[ff] = fmaf(w0, hv[ff], fmaf(w1, hv[ff + 1], fmaf(w2, hv[ff + 2], bg[oc])));
      float* dst = out + ((size_t)btl * OCT + oc) * 64 + f0;
      *(float4*)dst = make_float4(acc[0], acc[1], acc[2], acc[3]);
      *(float4*)(dst + 4) = make_float4(acc[4], acc[5], acc[6], acc[7]);
    }
#pragma unroll
    for (int j = 0; j < NJC; ++j) {
      const int oc = ocg + 32 * j;
      const float w0 = Wcx[oc * 3], w1 = Wcx[oc * 3 + 1], w2 = Wcx[oc * 3 + 2];
      float acc[8];
#pragma unroll
      for (int ff = 0; ff < 8; ++ff)
        acc[ff] = fmaf(w0, hv[ff], fmaf(w1, hv[ff + 1], fmaf(w2, hv[ff + 2], bc[oc])));
      float* dst = out + ((size_t)btl * OCT + OG + oc) * 64 + f0;
      *(float4*)dst = make_float4(acc[0], acc[1], acc[2], acc[3]);
      *(float4*)(dst + 4) = make_float4(acc[4], acc[5], acc[6], acc[7]);
    }
  }
}

template <int INC, int OG, int OCC>
__global__ __launch_bounds__(256) void conv_x_kernel(
    const float* __restrict__ seq, int seqC, size_t sB,
    const float* __restrict__ ctx,
    const float* __restrict__ Wgx, const float* __restrict__ Wcx,
    const float* __restrict__ bg, const float* __restrict__ bc,
    float* __restrict__ out) {
  __shared__ float sin_[INC][72];
  conv_x_body<INC, OG, OCC>(sin_, threadIdx.x, blockIdx.x, seq, seqC, sB, ctx,
                            Wgx, Wcx, bg, bc, out);
}

// --------------------------------------------------------------------------
// Final 1x1 conv body: one 256-wide tile.
// --------------------------------------------------------------------------
__device__ __forceinline__ void final_body(
    int tid, int tile, const float* __restrict__ z1c,
    const float* __restrict__ wfin, const float* __restrict__ bfin,
    float* __restrict__ out, int tOff) {
  const int idx = tile * 256 + tid;
  const int f = idx & 63;
  const int tl = (idx >> 6) & 31;
  const int b = idx >> 11;
  const float* zp = z1c + ((size_t)b * TC + tl) * 2048 + f;
  float a = bfin[0];
#pragma unroll
  for (int c = 0; c < 32; ++c) a = fmaf(wfin[c], zp[c * 64], a);
  out[(size_t)b * 8192 + (size_t)(tOff + tl) * 64 + f] = a;
}

__global__ __launch_bounds__(256) void final_kernel(
    const float* __restrict__ z1c,
    const float* __restrict__ wfin, const float* __restrict__ bfin,
    float* __restrict__ out, int tOff) {
  final_body(threadIdx.x, blockIdx.x, z1c, wfin, bfin, out, tOff);
}

// --------------------------------------------------------------------------
// GRU recurrence body (R4-exact) + s_setprio(1) around the main loop so
// critical-path gru waves win issue arbitration over co-resident conv waves.
// --------------------------------------------------------------------------
template <int HC>
__device__ __forceinline__ void gru_body(
    float* smem,
    const float* __restrict__ A, const float* __restrict__ Wgh,
    const float* __restrict__ Wch, const float* hinit,
    float* __restrict__ Y, size_t yB, float* hfinal, int b) {
  constexpr int NR = HC / 32;
  constexpr int OG = 2 * HC;
  constexpr int OCT = 3 * HC;
  float(*Hs)[68] = (float(*)[68])smem;
  float(*Rs)[68] = (float(*)[68])(smem + HC * 68);
  const int tid = threadIdx.x;
  const int ocg = tid >> 4;
  const int f0 = (tid & 15) << 2;
  const int im = (f0 == 0) ? 0 : f0 - 1;
  const bool lo = (f0 == 0), hi = (f0 == 60);

  float hreg[NR][4];
#pragma unroll
  for (int r = 0; r < NR; ++r) {
    const int oc = ocg + 32 * r;
    const float4 v = *(const float4*)(hinit + ((size_t)b * HC + oc) * 64 + f0);
    hreg[r][0] = v.x; hreg[r][1] = v.y; hreg[r][2] = v.z; hreg[r][3] = v.w;
    *(float4*)&Hs[oc][f0] = v;
  }
  __syncthreads();
  __builtin_amdgcn_s_setprio(1);

  for (int tl = 0; tl < TC; ++tl) {
    const float* Abt = A + ((size_t)b * TC + tl) * (OCT * 64);
    float accr[NR][4], accu[NR][4], accc[NR][4];
#pragma unroll
    for (int r = 0; r < NR; ++r) {
      const int oc = ocg + 32 * r;
      const float4 vr = *(const float4*)(Abt + (size_t)oc * 64 + f0);
      const float4 vu = *(const float4*)(Abt + (size_t)(HC + oc) * 64 + f0);
      const float4 vc = *(const float4*)(Abt + (size_t)(OG + oc) * 64 + f0);
      accr[r][0] = vr.x; accr[r][1] = vr.y; accr[r][2] = vr.z; accr[r][3] = vr.w;
      accu[r][0] = vu.x; accu[r][1] = vu.y; accu[r][2] = vu.z; accu[r][3] = vu.w;
      accc[r][0] = vc.x; accc[r][1] = vc.y; accc[r][2] = vc.z; accc[r][3] = vc.w;
    }
#pragma unroll 2
    for (int hc0 = 0; hc0 < HC; hc0 += 4) {
      float hv[4][6];
#pragma unroll
      for (int q = 0; q < 4; ++q) {
        const float4 h4 = *(const float4*)&Hs[hc0 + q][f0];
        const float lf = Hs[hc0 + q][im];
        const float rt = Hs[hc0 + q][f0 + 4];
        hv[q][0] = lo ? 0.f : lf;
        hv[q][1] = h4.x; hv[q][2] = h4.y; hv[q][3] = h4.z; hv[q][4] = h4.w;
        hv[q][5] = hi ? 0.f : rt;
      }
#pragma unroll
      for (int r = 0; r < NR; ++r) {
        {
          const float4* w4 = (const float4*)(Wgh + ((size_t)(ocg + 32 * r) * HC + hc0) * 3);
          const float4 wa = w4[0], wb = w4[1], wc4 = w4[2];
          const float wt[12] = {wa.x, wa.y, wa.z, wa.w, wb.x, wb.y, wb.z, wb.w,
                                wc4.x, wc4.y, wc4.z, wc4.w};
#pragma unroll
          for (int q = 0; q < 4; ++q) {
            const float w0 = wt[3 * q], w1 = wt[3 * q + 1], w2 = wt[3 * q + 2];
#pragma unroll
            for (int ff = 0; ff < 4; ++ff)
              accr[r][ff] = fmaf(w0, hv[q][ff], fmaf(w1, hv[q][ff + 1], fmaf(w2, hv[q][ff + 2], accr[r][ff])));
          }
        }
        {
          const float4* w4 = (const float4*)(Wgh + ((size_t)(HC + ocg + 32 * r) * HC + hc0) * 3);
          const float4 wa = w4[0], wb = w4[1], wc4 = w4[2];
          const float wt[12] = {wa.x, wa.y, wa.z, wa.w, wb.x, wb.y, wb.z, wb.w,
                                wc4.x, wc4.y, wc4.z, wc4.w};
#pragma unroll
          for (int q = 0; q < 4; ++q) {
            const float w0 = wt[3 * q], w1 = wt[3 * q + 1], w2 = wt[3 * q + 2];
#pragma unroll
            for (int ff = 0; ff < 4; ++ff)
              accu[r][ff] = fmaf(w0, hv[q][ff], fmaf(w1, hv[q][ff + 1], fmaf(w2, hv[q][ff + 2], accu[r][ff])));
          }
        }
      }
    }
    float uu[NR][4];
#pragma unroll
    for (int r = 0; r < NR; ++r) {
      float4 rh;
#pragma unroll
      for (int ff = 0; ff < 4; ++ff) {
        uu[r][ff] = sigmoidf_(accu[r][ff]);
        (&rh.x)[ff] = sigmoidf_(accr[r][ff]) * hreg[r][ff];
      }
      *(float4*)&Rs[ocg + 32 * r][f0] = rh;
    }
    __syncthreads();
#pragma unroll 2
    for (int hc0 = 0; hc0 < HC; hc0 += 4) {
      float hv[4][6];
#pragma unroll
      for (int q = 0; q < 4; ++q) {
        const float4 h4 = *(const float4*)&Rs[hc0 + q][f0];
        const float lf = Rs[hc0 + q][im];
        const float rt = Rs[hc0 + q][f0 + 4];
        hv[q][0] = lo ? 0.f : lf;
        hv[q][1] = h4.x; hv[q][2] = h4.y; hv[q][3] = h4.z; hv[q][4] = h4.w;
        hv[q][5] = hi ? 0.f : rt;
      }
#pragma unroll
      for (int r = 0; r < NR; ++r) {
        const float4* w4 = (const float4*)(Wch + ((size_t)(ocg + 32 * r) * HC + hc0) * 3);
        const float4 wa = w4[0], wb = w4[1], wc4 = w4[2];
        const float wt[12] = {wa.x, wa.y, wa.z, wa.w, wb.x, wb.y, wb.z, wb.w,
                              wc4.x, wc4.y, wc4.z, wc4.w};
#pragma unroll
        for (int q = 0; q < 4; ++q) {
          const float w0 = wt[3 * q], w1 = wt[3 * q + 1], w2 = wt[3 * q + 2];
#pragma unroll
          for (int ff = 0; ff < 4; ++ff)
            accc[r][ff] = fmaf(w0, hv[q][ff], fmaf(w1, hv[q][ff + 1], fmaf(w2, hv[q][ff + 2], accc[r][ff])));
        }
      }
    }
#pragma unroll
    for (int r = 0; r < NR; ++r) {
      const int oc = ocg + 32 * r;
      float4 yv;
#pragma unroll
      for (int ff = 0; ff < 4; ++ff) {
        const float cd = tanhf_(accc[r][ff]);
        const float hn = fmaf(uu[r][ff], cd - hreg[r][ff], hreg[r][ff]);
        hreg[r][ff] = hn;
        (&yv.x)[ff] = hn;
      }
      *(float4*)(Y + (size_t)b * yB + (size_t)tl * (HC * 64) + (size_t)oc * 64 + f0) = yv;
      *(float4*)&Hs[oc][f0] = yv;
    }
    __syncthreads();
  }
  __builtin_amdgcn_s_setprio(0);
#pragma unroll
  for (int r = 0; r < NR; ++r) {
    const int oc = ocg + 32 * r;
    *(float4*)(hfinal + ((size_t)b * HC + oc) * 64 + f0) =
        make_float4(hreg[r][0], hreg[r][1], hreg[r][2], hreg[r][3]);
  }
}

template <int HC>
__global__ __launch_bounds__(512) void gru_rec_kernel(
    const float* __restrict__ A, const float* __restrict__ Wgh,
    const float* __restrict__ Wch, const float* hinit,
    float* __restrict__ Y, size_t yB, float* hfinal) {
  __shared__ float smem[2 * HC * 68];
  gru_body<HC>(smem, A, Wgh, Wch, hinit, Y, yB, hfinal, blockIdx.x);
}

struct GruArgs {
  const float* A;
  const float* Wgh;
  const float* Wch;
  const float* hinit;
  float* Y;
  size_t yB;
  float* hfinal;
};

// R9 heterogeneous gru-only fusion (encoder).
__global__ __launch_bounds__(512) void gru_fused_kernel(GruArgs g64, GruArgs g32) {
  __shared__ float smem[2 * 64 * 68];
  if (blockIdx.x < 64) {
    gru_body<64>(smem, g64.A, g64.Wgh, g64.Wch, g64.hinit, g64.Y, g64.yB,
                 g64.hfinal, blockIdx.x);
  } else {
    gru_body<32>(smem, g32.A, g32.Wgh, g32.Wch, g32.hinit, g32.Y, g32.yB,
                 g32.hfinal, blockIdx.x - 64);
  }
}

// --------------------------------------------------------------------------
// Mega kernel: gru64 blocks + gru32 blocks + conv/final job tiles.
// 512 threads; conv/final jobs run as 2x 256-thread tiles per block.
// kinds: 2 = conv_d0 (INC128), 3 = conv_d1 (INC64), 4 = final.
// --------------------------------------------------------------------------
struct ConvJob {
  int kind;
  int nblk;          // 512-thread blocks = tiles/2
  const float* seq;
  int seqC;
  size_t sB;
  const float* ctx;
  const float* w0;
  const float* w1;
  const float* b0;
  const float* b1;
  float* out;
  int tOff;
};

struct MegaArgs {
  GruArgs g64;
  GruArgs g32;
  int ng64, ng32, njobs;
  ConvJob jobs[4];
};

__global__ __launch_bounds__(512) void mega_kernel(MegaArgs ma) {
  __shared__ float smem[18432];  // max(2*64*68 gru, 2*128*72 conv_d0) floats
  int bid = blockIdx.x;
  if (bid < ma.ng64) {
    gru_body<64>(smem, ma.g64.A, ma.g64.Wgh, ma.g64.Wch, ma.g64.hinit,
                 ma.g64.Y, ma.g64.yB, ma.g64.hfinal, bid);
    return;
  }
  bid -= ma.ng64;
  if (bid < ma.ng32) {
    gru_body<32>(smem, ma.g32.A, ma.g32.Wgh, ma.g32.Wch, ma.g32.hinit,
                 ma.g32.Y, ma.g32.yB, ma.g32.hfinal, bid);
    return;
  }
  bid -= ma.ng32;
  const int half = threadIdx.x >> 8;
  const int tid = threadIdx.x & 255;
#pragma unroll 1
  for (int j = 0; j < ma.njobs; ++j) {
    if (bid < ma.jobs[j].nblk) {
      const ConvJob cj = ma.jobs[j];
      const int tile = bid * 2 + half;
      if (cj.kind == 2) {
        conv_x_body<128, 128, 64>((float(*)[72])(smem + half * 128 * 72), tid,
                                  tile, cj.seq, cj.seqC, cj.sB, cj.ctx, cj.w0,
                                  cj.w1, cj.b0, cj.b1, cj.out);
      } else if (cj.kind == 3) {
        conv_x_body<64, 64, 32>((float(*)[72])(smem + half * 64 * 72), tid,
                                tile, cj.seq, cj.seqC, cj.sB, cj.ctx, cj.w0,
                                cj.w1, cj.b0, cj.b1, cj.out);
      } else {
        final_body(tid, tile, cj.seq, cj.w0, cj.b0, cj.out, cj.tOff);
      }
      return;
    }
    bid -= ma.jobs[j].nblk;
  }
}

// --------------------------------------------------------------------------
// Small fp32 GEMM: O[b][e] = sum_k W[e][k]*X[b][k] + bias[e], M=64.
// --------------------------------------------------------------------------
template <bool WT>
__global__ __launch_bounds__(256) void gemm64_kernel(
    const float* __restrict__ W, int wrs,
    const float* __restrict__ X, int xrs,
    float* __restrict__ O, int ors,
    const float* __restrict__ bias, int K,
    int ebh, size_t hsW, size_t hsX, size_t hsO, size_t hsB) {
  int eb = blockIdx.x;
  if (ebh > 0) {
    int h = blockIdx.x / ebh;
    eb = blockIdx.x - h * ebh;
    W += h * hsW; X += h * hsX; O += h * hsO;
    if (bias) bias += h * hsB;
  }
  const int e0 = eb * 64;
  __shared__ float Xs[64][68];
  __shared__ float Ws[64][68];
  const int tb4 = (threadIdx.x & 15) << 2;
  const int te4 = (threadIdx.x >> 4) << 2;
  float acc[4][4] = {};
  for (int k0 = 0; k0 < K; k0 += 64) {
    {
      const int row = threadIdx.x >> 2;
      const int kq = (threadIdx.x & 3) << 4;
      const float* src = X + (size_t)row * xrs + k0 + kq;
#pragma unroll
      for (int q = 0; q < 4; ++q) {
        float4 v = *(const float4*)(src + (q << 2));
        Xs[kq + (q << 2) + 0][row] = v.x;
        Xs[kq + (q << 2) + 1][row] = v.y;
        Xs[kq + (q << 2) + 2][row] = v.z;
        Xs[kq + (q << 2) + 3][row] = v.w;
      }
    }
    if (!WT) {
      const int row = threadIdx.x >> 2;
      const int kq = (threadIdx.x & 3) << 4;
      const float* src = W + (size_t)(e0 + row) * wrs + k0 + kq;
#pragma unroll
      for (int q = 0; q < 4; ++q) {
        float4 v = *(const float4*)(src + (q << 2));
        Ws[kq + (q << 2) + 0][row] = v.x;
        Ws[kq + (q << 2) + 1][row] = v.y;
        Ws[kq + (q << 2) + 2][row] = v.z;
        Ws[kq + (q << 2) + 3][row] = v.w;
      }
    } else {
      const int row = threadIdx.x >> 2;
      const int eq = (threadIdx.x & 3) << 4;
      const float* src = W + (size_t)(k0 + row) * wrs + e0 + eq;
#pragma unroll
      for (int q = 0; q < 4; ++q)
        *(float4*)&Ws[row][eq + (q << 2)] = *(const float4*)(src + (q << 2));
    }
    __syncthreads();
#pragma unroll 8
    for (int k = 0; k < 64; ++k) {
      float4 xv = *(const float4*)&Xs[k][tb4];
      float4 wv4 = *(const float4*)&Ws[k][te4];
      const float xb[4] = {xv.x, xv.y, xv.z, xv.w};
      const float we[4] = {wv4.x, wv4.y, wv4.z, wv4.w};
#pragma unroll
      for (int i = 0; i < 4; ++i)
#pragma unroll
        for (int j = 0; j < 4; ++j) acc[i][j] = fmaf(xb[i], we[j], acc[i][j]);
    }
    __syncthreads();
  }
#pragma unroll
  for (int i = 0; i < 4; ++i)
#pragma unroll
    for (int j = 0; j < 4; ++j) {
      float v = acc[i][j];
      if (bias) v += bias[e0 + te4 + j];
      O[(size_t)(tb4 + i) * ors + e0 + te4 + j] = v;
    }
}

// --------------------------------------------------------------------------
// Attention, parallel form (qlen==1, folded).
// --------------------------------------------------------------------------
__global__ __launch_bounds__(256) void attn_scores_kernel(
    const float* __restrict__ qkh, const float* __restrict__ mem,
    float* __restrict__ scores) {
  const int b = blockIdx.x >> 4;
  const int tt = blockIdx.x & 15;
  const int h = threadIdx.x >> 6;
  const int lane = threadIdx.x & 63;
  const float4* qk4 = (const float4*)(qkh + ((size_t)b * 4 + h) * 4096);
#pragma unroll 2
  for (int ti = 0; ti < 8; ++ti) {
    const int t = tt * 8 + ti;
    const float4* m4 = (const float4*)(mem + ((size_t)b * 128 + t) * 4096);
    float s = 0.f;
    for (int e = lane; e < 1024; e += 64) {
      float4 q = qk4[e], m = m4[e];
      s = fmaf(q.x, m.x, fmaf(q.y, m.y, fmaf(q.z, m.z, fmaf(q.w, m.w, s))));
    }
    s = wsum(s);
    if (lane == 0) scores[((size_t)b * 4 + h) * 128 + t] = s;
  }
}

__global__ __launch_bounds__(256) void attn_softmax_kernel(
    const float* __restrict__ scores, const float* __restrict__ qbuf,
    const float* __restrict__ bqkv, float* __restrict__ attnp) {
  const int b = blockIdx.x;
  const int h = threadIdx.x >> 6;
  const int lane = threadIdx.x & 63;
  const float4* q4 = (const float4*)(qbuf + (size_t)b * 4096 + h * 1024);
  const float4* k4 = (const float4*)(bqkv + 4096 + h * 1024);
  float qb = 0.f;
#pragma unroll
  for (int d = lane; d < 256; d += 64) {
    float4 q = q4[d], k = k4[d];
    qb = fmaf(q.x, k.x, fmaf(q.y, k.y, fmaf(q.z, k.z, fmaf(q.w, k.w, qb))));
  }
  qb = wsum(qb);
  const float* sc = scores + ((size_t)b * 4 + h) * 128;
  float s0 = (sc[lane] + qb) * 0.03125f;
  float s1 = (sc[lane + 64] + qb) * 0.03125f;
  float mx = wmaxr(fmaxf(s0, s1));
  float e0v = __expf(s0 - mx), e1v = __expf(s1 - mx);
  float inv = 1.f / wsum(e0v + e1v);
  attnp[((size_t)b * 4 + h) * 128 + lane] = e0v * inv;
  attnp[((size_t)b * 4 + h) * 128 + lane + 64] = e1v * inv;
}

__global__ __launch_bounds__(256) void attn_wsum_kernel(
    const float* __restrict__ attnp, const float* __restrict__ mem,
    float* __restrict__ wmem) {
  const int b = blockIdx.x >> 4;
  const int eb = blockIdx.x & 15;
  const int e = eb * 256 + threadIdx.x;
  __shared__ float ap[4][128];
  for (int i = threadIdx.x; i < 512; i += 256)
    ap[i >> 7][i & 127] = attnp[(size_t)b * 512 + i];
  __syncthreads();
  float a0 = 0, a1 = 0, a2 = 0, a3 = 0;
  const float* mb = mem + (size_t)b * 128 * 4096 + e;
#pragma unroll 4
  for (int t = 0; t < 128; ++t) {
    float m = mb[(size_t)t * 4096];
    a0 = fmaf(ap[0][t], m, a0);
    a1 = fmaf(ap[1][t], m, a1);
    a2 = fmaf(ap[2][t], m, a2);
    a3 = fmaf(ap[3][t], m, a3);
  }
  wmem[((size_t)b * 4 + 0) * 4096 + e] = a0;
  wmem[((size_t)b * 4 + 1) * 4096 + e] = a1;
  wmem[((size_t)b * 4 + 2) * 4096 + e] = a2;
  wmem[((size_t)b * 4 + 3) * 4096 + e] = a3;
}

// ==========================================================================
extern "C" void kernel_launch(void* const* d_in, const int* in_sizes, int n_in,
                              void* d_out, int out_size, void* d_ws, size_t ws_size,
                              hipStream_t stream) {
  (void)in_sizes; (void)n_in; (void)out_size;
  const float* x     = (const float*)d_in[0];
  const float* wg_e0 = (const float*)d_in[1];
  const float* bg_e0 = (const float*)d_in[2];
  const float* wc_e0 = (const float*)d_in[3];
  const float* bc_e0 = (const float*)d_in[4];
  const float* wg_e1 = (const float*)d_in[5];
  const float* bg_e1 = (const float*)d_in[6];
  const float* wc_e1 = (const float*)d_in[7];
  const float* bc_e1 = (const float*)d_in[8];
  const float* wg_d0 = (const float*)d_in[9];
  const float* bg_d0 = (const float*)d_in[10];
  const float* wc_d0 = (const float*)d_in[11];
  const float* bc_d0 = (const float*)d_in[12];
  const float* wg_d1 = (const float*)d_in[13];
  const float* bg_d1 = (const float*)d_in[14];
  const float* wc_d1 = (const float*)d_in[15];
  const float* bc_d1 = (const float*)d_in[16];
  const float* w_qkv = (const float*)d_in[17];
  const float* b_qkv = (const float*)d_in[18];
  const float* w_out = (const float*)d_in[19];
  const float* b_out = (const float*)d_in[20];
  const float* w_fin = (const float*)d_in[21];
  const float* b_fin = (const float*)d_in[22];
  float* out = (float*)d_out;

  float* WS = (float*)d_ws;
  size_t off = 0;
  auto alloc = [&](size_t n) { float* p = WS + off; off += (n + 63) & ~(size_t)63; return p; };
  float* Amp0 = alloc((size_t)B_ * TC * 192 * 64);
  float* A960 = alloc((size_t)B_ * TC * 96 * 64);
  float* Y0c  = alloc((size_t)B_ * TC * 32 * 64);
  float* Y1   = alloc((size_t)B_ * T_ * 64 * 64);
  float* Z0p[2] = {alloc((size_t)B_ * TC * 64 * 64), alloc((size_t)B_ * TC * 64 * 64)};
  float* Z1p0 = alloc((size_t)B_ * TC * 32 * 64);
  float* He0p[2] = {alloc((size_t)B_ * 32 * 64), alloc((size_t)B_ * 32 * 64)};
  float* He1p[2] = {alloc((size_t)B_ * 64 * 64), alloc((size_t)B_ * 64 * 64)};
  float* Hd0p[2] = {alloc((size_t)B_ * 64 * 64), alloc((size_t)B_ * 64 * 64)};
  float* Hd1p[2] = {alloc((size_t)B_ * 32 * 64), alloc((size_t)B_ * 32 * 64)};
  float* QBUF = alloc((size_t)B_ * 4096);
  float* QKH  = alloc((size_t)B_ * 4 * 4096);
  float* WMEM = alloc((size_t)B_ * 4 * 4096);
  float* CTXB = alloc((size_t)B_ * 4096);
  float* CTXO = alloc((size_t)B_ * 4096);
  float* SCR  = alloc((size_t)B_ * 4 * 128);
  float* ATTN = alloc((size_t)B_ * 4 * 128);
  float* wgx_e0 = alloc(64 * 1 * 3);    float* wgh_e0 = alloc(64 * 32 * 3);
  float* wcx_e0 = alloc(32 * 1 * 3);    float* wch_e0 = alloc(32 * 32 * 3);
  float* wgx_e1 = alloc(128 * 32 * 3);  float* wgh_e1 = alloc(128 * 64 * 3);
  float* wcx_e1 = alloc(64 * 32 * 3);   float* wch_e1 = alloc(64 * 64 * 3);
  float* wgx_d0 = alloc(128 * 128 * 3); float* wgh_d0 = alloc(128 * 64 * 3);
  float* wcx_d0 = alloc(64 * 128 * 3);  float* wch_d0 = alloc(64 * 64 * 3);
  float* wgx_d1 = alloc(64 * 64 * 3);   float* wgh_d1 = alloc(64 * 32 * 3);
  float* wcx_d1 = alloc(32 * 64 * 3);   float* wch_d1 = alloc(32 * 32 * 3);
  const size_t off_r9 = off;
  float* Amp1 = alloc((size_t)B_ * TC * 192 * 64);
  float* A961 = alloc((size_t)B_ * TC * 96 * 64);
  float* Z1p1 = alloc((size_t)B_ * TC * 32 * 64);
  const size_t off_full = off;
  if (ws_size < off_r9 * sizeof(float)) return;
  const bool mega_ok = (ws_size >= off_full * sizeof(float));

  float* Amp[2] = {Amp0, Amp1};
  float* A96p[2] = {A960, A961};
  float* Z1p[2] = {Z1p0, Z1p1};

  // Fused weight repack (16 jobs, one launch).
  {
    PackArgs pa;
    const float* srcs[16] = {wg_e0, wg_e0, wc_e0, wc_e0, wg_e1, wg_e1, wc_e1, wc_e1,
                             wg_d0, wg_d0, wc_d0, wc_d0, wg_d1, wg_d1, wc_d1, wc_d1};
    float* dsts[16] = {wgx_e0, wgh_e0, wcx_e0, wch_e0, wgx_e1, wgh_e1, wcx_e1, wch_e1,
                       wgx_d0, wgh_d0, wcx_d0, wch_d0, wgx_d1, wgh_d1, wcx_d1, wch_d1};
    int intot[16] = {33, 33, 33, 33, 96, 96, 96, 96, 192, 192, 192, 192, 96, 96, 96, 96};
    int ic0[16]   = {0, 1, 0, 1, 0, 32, 0, 32, 0, 128, 0, 128, 0, 64, 0, 64};
    int icn[16]   = {1, 32, 1, 32, 32, 64, 32, 64, 128, 64, 128, 64, 64, 32, 64, 32};
    int occ[16]   = {64, 64, 32, 32, 128, 128, 64, 64, 128, 128, 64, 64, 64, 64, 32, 32};
    for (int j = 0; j < 16; ++j) {
      pa.src[j] = srcs[j]; pa.dst[j] = dsts[j];
      pa.intot[j] = intot[j]; pa.ic0[j] = ic0[j]; pa.icn[j] = icn[j]; pa.oc[j] = occ[j];
    }
    pack_all_kernel<<<dim3(192, 16), 256, 0, stream>>>(pa);
  }

  hipMemsetAsync(He0p[0], 0, (size_t)B_ * 32 * 64 * 4, stream);
  hipMemsetAsync(He1p[0], 0, (size_t)B_ * 64 * 64 * 4, stream);

  auto conv_e0 = [&](int c) {
    conv_x_kernel<1, 64, 32><<<2048, 256, 0, stream>>>(
        x + (size_t)c * TC * 64, 1, (size_t)T_ * 64, nullptr,
        wgx_e0, wcx_e0, bg_e0, bc_e0, A96p[0]);
  };
  auto conv_e1 = [&]() {
    conv_x_kernel<32, 128, 64><<<2048, 256, 0, stream>>>(
        Y0c, 32, (size_t)TC * 32 * 64, nullptr,
        wgx_e1, wcx_e1, bg_e1, bc_e1, Amp[0]);
  };

  // -------- encoder (R9-exact: gru64(c) fused with gru32(c+1)) --------
  conv_e0(0);
  gru_rec_kernel<32><<<64, 512, 0, stream>>>(
      A96p[0], wgh_e0, wch_e0, He0p[0], Y0c, (size_t)TC * 2048, He0p[1]);
  conv_e1();
  for (int c = 0; c < NCH; ++c) {
    GruArgs g64 = {Amp[0], wgh_e1, wch_e1, He1p[c & 1],
                   Y1 + (size_t)c * TC * 4096, (size_t)T_ * 4096, He1p[(c + 1) & 1]};
    if (c < NCH - 1) {
      conv_e0(c + 1);
      GruArgs g32 = {A96p[0], wgh_e0, wch_e0, He0p[(c + 1) & 1],
                     Y0c, (size_t)TC * 2048, He0p[c & 1]};
      gru_fused_kernel<<<128, 512, 0, stream>>>(g64, g32);
      conv_e1();
    } else {
      gru_rec_kernel<64><<<64, 512, 0, stream>>>(
          g64.A, g64.Wgh, g64.Wch, g64.hinit, g64.Y, g64.yB, g64.hfinal);
    }
  }
  float* He0f = He0p[0];
  float* He1f = He1p[0];

  // -------- attention (query len 1, folded) --------
  const float* wq = w_qkv;
  const float* wk = w_qkv + (size_t)4096 * 4096;
  const float* wv = w_qkv + (size_t)8192 * 4096;
  gemm64_kernel<false><<<64, 256, 0, stream>>>(wq, 4096, He1f, 4096, QBUF, 4096,
                                               b_qkv, 4096, 0, 0, 0, 0, 0);
  gemm64_kernel<true><<<256, 256, 0, stream>>>(wk, 4096, QBUF, 4096, QKH, 16384,
                                               nullptr, 1024, 64,
                                               (size_t)1024 * 4096, 1024, 4096, 0);
  attn_scores_kernel<<<B_ * 16, 256, 0, stream>>>(QKH, Y1, SCR);
  attn_softmax_kernel<<<B_, 256, 0, stream>>>(SCR, QBUF, b_qkv, ATTN);
  attn_wsum_kernel<<<B_ * 16, 256, 0, stream>>>(ATTN, Y1, WMEM);
  gemm64_kernel<false><<<64, 256, 0, stream>>>(wv, 4096, WMEM, 16384, CTXB, 4096,
                                               b_qkv + 8192, 4096, 16,
                                               (size_t)1024 * 4096, 4096, 1024, 1024);
  gemm64_kernel<false><<<64, 256, 0, stream>>>(w_out, 4096, CTXB, 4096, CTXO, 4096,
                                               b_out, 4096, 0, 0, 0, 0, 0);

  // -------- decoder --------
  if (mega_ok) {
    auto JD0 = [&](int c, float* dst) {
      ConvJob j{}; j.kind = 2; j.nblk = 1024;
      j.seq = Y1 + (size_t)c * TC * 4096; j.seqC = 64; j.sB = (size_t)T_ * 4096;
      j.ctx = CTXO; j.w0 = wgx_d0; j.w1 = wcx_d0; j.b0 = bg_d0; j.b1 = bc_d0;
      j.out = dst; return j;
    };
    auto JD1 = [&](float* z0src, float* dst) {
      ConvJob j{}; j.kind = 3; j.nblk = 1024;
      j.seq = z0src; j.seqC = 64; j.sB = (size_t)TC * 4096;
      j.ctx = nullptr; j.w0 = wgx_d1; j.w1 = wcx_d1; j.b0 = bg_d1; j.b1 = bc_d1;
      j.out = dst; return j;
    };
    auto JFIN = [&](float* z1src, int tOff) {
      ConvJob j{}; j.kind = 4; j.nblk = 256;
      j.seq = z1src; j.w0 = w_fin; j.b0 = b_fin; j.out = out; j.tOff = tOff;
      return j;
    };
    auto mega = [&](const GruArgs* a64, const GruArgs* a32, int nj,
                    const ConvJob* js) {
      MegaArgs ma{};
      ma.ng64 = a64 ? 64 : 0; if (a64) ma.g64 = *a64;
      ma.ng32 = a32 ? 64 : 0; if (a32) ma.g32 = *a32;
      ma.njobs = nj;
      int grid = ma.ng64 + ma.ng32;
      for (int i = 0; i < nj; ++i) { ma.jobs[i] = js[i]; grid += js[i].nblk; }
      mega_kernel<<<grid, 512, 0, stream>>>(ma);
    };

    GruArgs gd0[4], gd1[4];
    for (int c = 0; c < 4; ++c) {
      gd0[c] = {Amp[c & 1], wgh_d0, wch_d0,
                (c == 0 ? He1f : Hd0p[c & 1]),
                Z0p[c & 1], (size_t)TC * 4096, Hd0p[(c + 1) & 1]};
      gd1[c] = {A96p[c & 1], wgh_d1, wch_d1,
                (c == 0 ? He0f : Hd1p[c & 1]),
                Z1p[c & 1], (size_t)TC * 2048, Hd1p[(c + 1) & 1]};
    }

    conv_x_kernel<128, 128, 64><<<2048, 256, 0, stream>>>(
        Y1, 64, (size_t)T_ * 4096, CTXO, wgx_d0, wcx_d0, bg_d0, bc_d0, Amp[0]);
    { ConvJob js[1] = {JD0(1, Amp[1])};
      mega(&gd0[0], nullptr, 1, js); }                                   // D1
    { ConvJob js[2] = {JD1(Z0p[0], A96p[0]), JD0(2, Amp[0])};
      mega(&gd0[1], nullptr, 2, js); }                                   // D2
    { ConvJob js[2] = {JD1(Z0p[1], A96p[1]), JD0(3, Amp[1])};
      mega(&gd0[2], &gd1[0], 2, js); }                                   // D3
    { ConvJob js[2] = {JD1(Z0p[0], A96p[0]), JFIN(Z1p[0], 0)};
      mega(&gd0[3], &gd1[1], 2, js); }                                   // D4
    { ConvJob js[2] = {JD1(Z0p[1], A96p[1]), JFIN(Z1p[1], TC)};
      mega(nullptr, &gd1[2], 2, js); }                                   // D5
    { ConvJob js[1] = {JFIN(Z1p[0], 2 * TC)};
      mega(nullptr, &gd1[3], 1, js); }                                   // D6
    final_kernel<<<512, 256, 0, stream>>>(Z1p[1], w_fin, b_fin, out, 3 * TC);
  } else {
    // Fallback: R9 decoder (serial convs), single Z1 buffer.
    auto conv_d0 = [&](int c) {
      conv_x_kernel<128, 128, 64><<<2048, 256, 0, stream>>>(
          Y1 + (size_t)c * TC * 4096, 64, (size_t)T_ * 4096, CTXO,
          wgx_d0, wcx_d0, bg_d0, bc_d0, Amp[0]);
    };
    auto conv_d1 = [&](int c) {
      conv_x_kernel<64, 64, 32><<<2048, 256, 0, stream>>>(
          Z0p[c & 1], 64, (size_t)TC * 4096, nullptr,
          wgx_d1, wcx_d1, bg_d1, bc_d1, A96p[0]);
    };
    conv_d0(0);
    gru_rec_kernel<64><<<64, 512, 0, stream>>>(
        Amp[0], wgh_d0, wch_d0, He1f, Z0p[0], (size_t)TC * 4096, Hd0p[1]);
    conv_d1(0);
    for (int c = 1; c < NCH; ++c) {
      conv_d0(c);
      GruArgs g64 = {Amp[0], wgh_d0, wch_d0, Hd0p[c & 1],
                     Z0p[c & 1], (size_t)TC * 4096, Hd0p[(c + 1) & 1]};
      GruArgs g32 = {A96p[0], wgh_d1, wch_d1,
                     (c - 1 == 0 ? He0f : Hd1p[(c - 1) & 1]),
                     Z1p[0], (size_t)TC * 2048, Hd1p[c & 1]};
      gru_fused_kernel<<<128, 512, 0, stream>>>(g64, g32);
      final_kernel<<<512, 256, 0, stream>>>(Z1p[0], w_fin, b_fin, out, (c - 1) * TC);
      conv_d1(c);
    }
    gru_rec_kernel<32><<<64, 512, 0, stream>>>(
        A96p[0], wgh_d1, wch_d1, Hd1p[1], Z1p[0], (size_t)TC * 2048, Hd1p[0]);
    final_kernel<<<512, 256, 0, stream>>>(Z1p[0], w_fin, b_fin, out, 3 * TC);
  }
}

// Round 14
// 7280.126 us; speedup vs baseline: 1.0632x; 1.0610x over previous
//
#include <hip/hip_runtime.h>
#include <cstdint>

// ---------------------------------------------------------------------------
// ConvGRU-Attention autoencoder, fp32. B=64, T=128, F=64 (1-D k=3 conv over F).
//   * conv split: x-part precomputed (parallel), h-part sequential per batch.
//   * attention: qlen==1 -> fold W_k into query, W_v past softmax (exact).
//   * R14: TC=16 / NCH=8. Unpaired gru stages cost ~3*S*t32; halving S saves
//     ~0.5 ms. conv_e0 hoisted to ONE upfront launch (depends only on x).
//     Encoder: g32(0) + 8 fused stages (+serial conv_e1). Decoder: 10 mega
//     stages with gd0[k] || gd1[k-2] and JD0/JD1/JFIN jobs (parity-checked).
// ---------------------------------------------------------------------------

#define B_  64
#define T_  128
#define TC  16
#define NCH 8

__device__ __forceinline__ float wsum(float v) {
#pragma unroll
  for (int m = 32; m > 0; m >>= 1) v += __shfl_xor(v, m, 64);
  return v;
}
__device__ __forceinline__ float wmaxr(float v) {
#pragma unroll
  for (int m = 32; m > 0; m >>= 1) v = fmaxf(v, __shfl_xor(v, m, 64));
  return v;
}
__device__ __forceinline__ float sigmoidf_(float x) {
  return 1.f / (1.f + __expf(-x));
}
__device__ __forceinline__ float tanhf_(float x) {
  x = fminf(fmaxf(x, -15.f), 15.f);
  float e2 = __expf(2.f * x);
  return (e2 - 1.f) / (e2 + 1.f);
}

// --------------------------------------------------------------------------
// Fused weight repack: 16 jobs in one launch. grid = (192, 16).
// --------------------------------------------------------------------------
struct PackArgs {
  const float* src[16];
  float* dst[16];
  int intot[16];
  int ic0[16];
  int icn[16];
  int oc[16];
};

__global__ __launch_bounds__(256) void pack_all_kernel(PackArgs pa) {
  const int j = blockIdx.y;
  const int icN = pa.icn[j];
  const int total = pa.oc[j] * icN * 3;
  const int i = blockIdx.x * 256 + threadIdx.x;
  if (i >= total) return;
  const int per_oc = icN * 3;
  const int oc = i / per_oc;
  const int rem = i - oc * per_oc;
  const int ic = rem / 3, dk = rem - ic * 3;
  pa.dst[j][i] =
      pa.src[j][((size_t)(oc * pa.intot[j] + pa.ic0[j] + ic) * 3 + dk) * 3 + 1];
}

// --------------------------------------------------------------------------
// x-part conv body (gates then cand) for one (b,tl) tile. tid in [0,256).
// Output at out + oidx*OCT*64.
// --------------------------------------------------------------------------
template <int INC, int OG, int OCC>
__device__ __forceinline__ void conv_x_body(
    float (*sin_)[72], int tid, int b, int tl, int oidx,
    const float* __restrict__ seq, int seqC, size_t sB,
    const float* __restrict__ ctx,
    const float* __restrict__ Wgx, const float* __restrict__ Wcx,
    const float* __restrict__ bg, const float* __restrict__ bc,
    float* __restrict__ out) {
  constexpr int OCT = OG + OCC;
  constexpr int NJ = OG / 32;
  constexpr int NJC = OCC / 32;
  const int ocg = tid >> 3;
  const int f0 = (tid & 7) << 3;

  for (int idx = tid; idx < INC * 72; idx += 256) {
    int ic = idx / 72, ff = idx - ic * 72;
    float v = 0.f;
    if (ff >= 1 && ff <= 64) {
      int fs = ff - 1;
      v = (ic < seqC)
              ? seq[(size_t)b * sB + (size_t)tl * seqC * 64 + ic * 64 + fs]
              : ctx[((size_t)b * (INC - seqC) + (ic - seqC)) * 64 + fs];
    }
    sin_[ic][ff] = v;
  }
  __syncthreads();

  if constexpr (INC >= 4) {
    {
      float acc[NJ][8];
#pragma unroll
      for (int j = 0; j < NJ; ++j) {
        float bb = bg[ocg + 32 * j];
#pragma unroll
        for (int ff = 0; ff < 8; ++ff) acc[j][ff] = bb;
      }
      for (int ic0 = 0; ic0 < INC; ic0 += 4) {
        float hv[4][10];
#pragma unroll
        for (int q = 0; q < 4; ++q) {
          float4 a4 = *(const float4*)&sin_[ic0 + q][f0];
          float4 b4 = *(const float4*)&sin_[ic0 + q][f0 + 4];
          float2 c2 = *(const float2*)&sin_[ic0 + q][f0 + 8];
          hv[q][0] = a4.x; hv[q][1] = a4.y; hv[q][2] = a4.z; hv[q][3] = a4.w;
          hv[q][4] = b4.x; hv[q][5] = b4.y; hv[q][6] = b4.z; hv[q][7] = b4.w;
          hv[q][8] = c2.x; hv[q][9] = c2.y;
        }
#pragma unroll
        for (int j = 0; j < NJ; ++j) {
          const int oc = ocg + 32 * j;
          const float4* w4 = (const float4*)(Wgx + ((size_t)oc * INC + ic0) * 3);
          float4 wa = w4[0], wb = w4[1], wc4 = w4[2];
          const float wt[12] = {wa.x, wa.y, wa.z, wa.w, wb.x, wb.y, wb.z, wb.w,
                                wc4.x, wc4.y, wc4.z, wc4.w};
#pragma unroll
          for (int q = 0; q < 4; ++q) {
            const float w0 = wt[3 * q], w1 = wt[3 * q + 1], w2 = wt[3 * q + 2];
#pragma unroll
            for (int ff = 0; ff < 8; ++ff)
              acc[j][ff] = fmaf(w0, hv[q][ff], fmaf(w1, hv[q][ff + 1], fmaf(w2, hv[q][ff + 2], acc[j][ff])));
          }
        }
      }
#pragma unroll
      for (int j = 0; j < NJ; ++j) {
        float* dst = out + ((size_t)oidx * OCT + ocg + 32 * j) * 64 + f0;
        *(float4*)dst = make_float4(acc[j][0], acc[j][1], acc[j][2], acc[j][3]);
        *(float4*)(dst + 4) = make_float4(acc[j][4], acc[j][5], acc[j][6], acc[j][7]);
      }
    }
    {
      float acc[NJC][8];
#pragma unroll
      for (int j = 0; j < NJC; ++j) {
        float bb = bc[ocg + 32 * j];
#pragma unroll
        for (int ff = 0; ff < 8; ++ff) acc[j][ff] = bb;
      }
      for (int ic0 = 0; ic0 < INC; ic0 += 4) {
        float hv[4][10];
#pragma unroll
        for (int q = 0; q < 4; ++q) {
          float4 a4 = *(const float4*)&sin_[ic0 + q][f0];
          float4 b4 = *(const float4*)&sin_[ic0 + q][f0 + 4];
          float2 c2 = *(const float2*)&sin_[ic0 + q][f0 + 8];
          hv[q][0] = a4.x; hv[q][1] = a4.y; hv[q][2] = a4.z; hv[q][3] = a4.w;
          hv[q][4] = b4.x; hv[q][5] = b4.y; hv[q][6] = b4.z; hv[q][7] = b4.w;
          hv[q][8] = c2.x; hv[q][9] = c2.y;
        }
#pragma unroll
        for (int j = 0; j < NJC; ++j) {
          const int oc = ocg + 32 * j;
          const float4* w4 = (const float4*)(Wcx + ((size_t)oc * INC + ic0) * 3);
          float4 wa = w4[0], wb = w4[1], wc4 = w4[2];
          const float wt[12] = {wa.x, wa.y, wa.z, wa.w, wb.x, wb.y, wb.z, wb.w,
                                wc4.x, wc4.y, wc4.z, wc4.w};
#pragma unroll
          for (int q = 0; q < 4; ++q) {
            const float w0 = wt[3 * q], w1 = wt[3 * q + 1], w2 = wt[3 * q + 2];
#pragma unroll
            for (int ff = 0; ff < 8; ++ff)
              acc[j][ff] = fmaf(w0, hv[q][ff], fmaf(w1, hv[q][ff + 1], fmaf(w2, hv[q][ff + 2], acc[j][ff])));
          }
        }
      }
#pragma unroll
      for (int j = 0; j < NJC; ++j) {
        float* dst = out + ((size_t)oidx * OCT + OG + ocg + 32 * j) * 64 + f0;
        *(float4*)dst = make_float4(acc[j][0], acc[j][1], acc[j][2], acc[j][3]);
        *(float4*)(dst + 4) = make_float4(acc[j][4], acc[j][5], acc[j][6], acc[j][7]);
      }
    }
  } else {
    float hv[10];
    {
      float4 a4 = *(const float4*)&sin_[0][f0];
      float4 b4 = *(const float4*)&sin_[0][f0 + 4];
      float2 c2 = *(const float2*)&sin_[0][f0 + 8];
      hv[0] = a4.x; hv[1] = a4.y; hv[2] = a4.z; hv[3] = a4.w;
      hv[4] = b4.x; hv[5] = b4.y; hv[6] = b4.z; hv[7] = b4.w;
      hv[8] = c2.x; hv[9] = c2.y;
    }
#pragma unroll
    for (int j = 0; j < NJ; ++j) {
      const int oc = ocg + 32 * j;
      const float w0 = Wgx[oc * 3], w1 = Wgx[oc * 3 + 1], w2 = Wgx[oc * 3 + 2];
      float acc[8];
#pragma unroll
      for (int ff = 0; ff < 8; ++ff)
        acc[ff] = fmaf(w0, hv[ff], fmaf(w1, hv[ff + 1], fmaf(w2, hv[ff + 2], bg[oc])));
      float* dst = out + ((size_t)oidx * OCT + oc) * 64 + f0;
      *(float4*)dst = make_float4(acc[0], acc[1], acc[2], acc[3]);
      *(float4*)(dst + 4) = make_float4(acc[4], acc[5], acc[6], acc[7]);
    }
#pragma unroll
    for (int j = 0; j < NJC; ++j) {
      const int oc = ocg + 32 * j;
      const float w0 = Wcx[oc * 3], w1 = Wcx[oc * 3 + 1], w2 = Wcx[oc * 3 + 2];
      float acc[8];
#pragma unroll
      for (int ff = 0; ff < 8; ++ff)
        acc[ff] = fmaf(w0, hv[ff], fmaf(w1, hv[ff + 1], fmaf(w2, hv[ff + 2], bc[oc])));
      float* dst = out + ((size_t)oidx * OCT + OG + oc) * 64 + f0;
      *(float4*)dst = make_float4(acc[0], acc[1], acc[2], acc[3]);
      *(float4*)(dst + 4) = make_float4(acc[4], acc[5], acc[6], acc[7]);
    }
  }
}

// tdiv: blocks decompose as b = bid / tdiv, tl = bid % tdiv.
template <int INC, int OG, int OCC>
__global__ __launch_bounds__(256) void conv_x_kernel(
    const float* __restrict__ seq, int seqC, size_t sB,
    const float* __restrict__ ctx,
    const float* __restrict__ Wgx, const float* __restrict__ Wcx,
    const float* __restrict__ bg, const float* __restrict__ bc,
    float* __restrict__ out, int tdiv) {
  __shared__ float sin_[INC][72];
  const int b = blockIdx.x / tdiv;
  const int tl = blockIdx.x - b * tdiv;
  conv_x_body<INC, OG, OCC>(sin_, threadIdx.x, b, tl, blockIdx.x, seq, seqC,
                            sB, ctx, Wgx, Wcx, bg, bc, out);
}

// --------------------------------------------------------------------------
// Final 1x1 conv body: one 256-wide tile. (TC=16: tl = (idx>>6)&15, b>>10.)
// --------------------------------------------------------------------------
__device__ __forceinline__ void final_body(
    int tid, int tile, const float* __restrict__ z1c,
    const float* __restrict__ wfin, const float* __restrict__ bfin,
    float* __restrict__ out, int tOff) {
  const int idx = tile * 256 + tid;
  const int f = idx & 63;
  const int tl = (idx >> 6) & (TC - 1);
  const int b = idx >> 10;
  const float* zp = z1c + ((size_t)b * TC + tl) * 2048 + f;
  float a = bfin[0];
#pragma unroll
  for (int c = 0; c < 32; ++c) a = fmaf(wfin[c], zp[c * 64], a);
  out[(size_t)b * 8192 + (size_t)(tOff + tl) * 64 + f] = a;
}

__global__ __launch_bounds__(256) void final_kernel(
    const float* __restrict__ z1c,
    const float* __restrict__ wfin, const float* __restrict__ bfin,
    float* __restrict__ out, int tOff) {
  final_body(threadIdx.x, blockIdx.x, z1c, wfin, bfin, out, tOff);
}

// --------------------------------------------------------------------------
// GRU recurrence body (R4-exact; per-batch A stride aB; setprio(1) in loop).
// --------------------------------------------------------------------------
template <int HC>
__device__ __forceinline__ void gru_body(
    float* smem,
    const float* __restrict__ A, size_t aB,
    const float* __restrict__ Wgh, const float* __restrict__ Wch,
    const float* hinit,
    float* __restrict__ Y, size_t yB, float* hfinal, int b) {
  constexpr int NR = HC / 32;
  constexpr int OG = 2 * HC;
  constexpr int OCT = 3 * HC;
  float(*Hs)[68] = (float(*)[68])smem;
  float(*Rs)[68] = (float(*)[68])(smem + HC * 68);
  const int tid = threadIdx.x;
  const int ocg = tid >> 4;
  const int f0 = (tid & 15) << 2;
  const int im = (f0 == 0) ? 0 : f0 - 1;
  const bool lo = (f0 == 0), hi = (f0 == 60);

  float hreg[NR][4];
#pragma unroll
  for (int r = 0; r < NR; ++r) {
    const int oc = ocg + 32 * r;
    const float4 v = *(const float4*)(hinit + ((size_t)b * HC + oc) * 64 + f0);
    hreg[r][0] = v.x; hreg[r][1] = v.y; hreg[r][2] = v.z; hreg[r][3] = v.w;
    *(float4*)&Hs[oc][f0] = v;
  }
  __syncthreads();
  __builtin_amdgcn_s_setprio(1);

  for (int tl = 0; tl < TC; ++tl) {
    const float* Abt = A + (size_t)b * aB + (size_t)tl * (OCT * 64);
    float accr[NR][4], accu[NR][4], accc[NR][4];
#pragma unroll
    for (int r = 0; r < NR; ++r) {
      const int oc = ocg + 32 * r;
      const float4 vr = *(const float4*)(Abt + (size_t)oc * 64 + f0);
      const float4 vu = *(const float4*)(Abt + (size_t)(HC + oc) * 64 + f0);
      const float4 vc = *(const float4*)(Abt + (size_t)(OG + oc) * 64 + f0);
      accr[r][0] = vr.x; accr[r][1] = vr.y; accr[r][2] = vr.z; accr[r][3] = vr.w;
      accu[r][0] = vu.x; accu[r][1] = vu.y; accu[r][2] = vu.z; accu[r][3] = vu.w;
      accc[r][0] = vc.x; accc[r][1] = vc.y; accc[r][2] = vc.z; accc[r][3] = vc.w;
    }
#pragma unroll 2
    for (int hc0 = 0; hc0 < HC; hc0 += 4) {
      float hv[4][6];
#pragma unroll
      for (int q = 0; q < 4; ++q) {
        const float4 h4 = *(const float4*)&Hs[hc0 + q][f0];
        const float lf = Hs[hc0 + q][im];
        const float rt = Hs[hc0 + q][f0 + 4];
        hv[q][0] = lo ? 0.f : lf;
        hv[q][1] = h4.x; hv[q][2] = h4.y; hv[q][3] = h4.z; hv[q][4] = h4.w;
        hv[q][5] = hi ? 0.f : rt;
      }
#pragma unroll
      for (int r = 0; r < NR; ++r) {
        {
          const float4* w4 = (const float4*)(Wgh + ((size_t)(ocg + 32 * r) * HC + hc0) * 3);
          const float4 wa = w4[0], wb = w4[1], wc4 = w4[2];
          const float wt[12] = {wa.x, wa.y, wa.z, wa.w, wb.x, wb.y, wb.z, wb.w,
                                wc4.x, wc4.y, wc4.z, wc4.w};
#pragma unroll
          for (int q = 0; q < 4; ++q) {
            const float w0 = wt[3 * q], w1 = wt[3 * q + 1], w2 = wt[3 * q + 2];
#pragma unroll
            for (int ff = 0; ff < 4; ++ff)
              accr[r][ff] = fmaf(w0, hv[q][ff], fmaf(w1, hv[q][ff + 1], fmaf(w2, hv[q][ff + 2], accr[r][ff])));
          }
        }
        {
          const float4* w4 = (const float4*)(Wgh + ((size_t)(HC + ocg + 32 * r) * HC + hc0) * 3);
          const float4 wa = w4[0], wb = w4[1], wc4 = w4[2];
          const float wt[12] = {wa.x, wa.y, wa.z, wa.w, wb.x, wb.y, wb.z, wb.w,
                                wc4.x, wc4.y, wc4.z, wc4.w};
#pragma unroll
          for (int q = 0; q < 4; ++q) {
            const float w0 = wt[3 * q], w1 = wt[3 * q + 1], w2 = wt[3 * q + 2];
#pragma unroll
            for (int ff = 0; ff < 4; ++ff)
              accu[r][ff] = fmaf(w0, hv[q][ff], fmaf(w1, hv[q][ff + 1], fmaf(w2, hv[q][ff + 2], accu[r][ff])));
          }
        }
      }
    }
    float uu[NR][4];
#pragma unroll
    for (int r = 0; r < NR; ++r) {
      float4 rh;
#pragma unroll
      for (int ff = 0; ff < 4; ++ff) {
        uu[r][ff] = sigmoidf_(accu[r][ff]);
        (&rh.x)[ff] = sigmoidf_(accr[r][ff]) * hreg[r][ff];
      }
      *(float4*)&Rs[ocg + 32 * r][f0] = rh;
    }
    __syncthreads();
#pragma unroll 2
    for (int hc0 = 0; hc0 < HC; hc0 += 4) {
      float hv[4][6];
#pragma unroll
      for (int q = 0; q < 4; ++q) {
        const float4 h4 = *(const float4*)&Rs[hc0 + q][f0];
        const float lf = Rs[hc0 + q][im];
        const float rt = Rs[hc0 + q][f0 + 4];
        hv[q][0] = lo ? 0.f : lf;
        hv[q][1] = h4.x; hv[q][2] = h4.y; hv[q][3] = h4.z; hv[q][4] = h4.w;
        hv[q][5] = hi ? 0.f : rt;
      }
#pragma unroll
      for (int r = 0; r < NR; ++r) {
        const float4* w4 = (const float4*)(Wch + ((size_t)(ocg + 32 * r) * HC + hc0) * 3);
        const float4 wa = w4[0], wb = w4[1], wc4 = w4[2];
        const float wt[12] = {wa.x, wa.y, wa.z, wa.w, wb.x, wb.y, wb.z, wb.w,
                              wc4.x, wc4.y, wc4.z, wc4.w};
#pragma unroll
        for (int q = 0; q < 4; ++q) {
          const float w0 = wt[3 * q], w1 = wt[3 * q + 1], w2 = wt[3 * q + 2];
#pragma unroll
          for (int ff = 0; ff < 4; ++ff)
            accc[r][ff] = fmaf(w0, hv[q][ff], fmaf(w1, hv[q][ff + 1], fmaf(w2, hv[q][ff + 2], accc[r][ff])));
        }
      }
    }
#pragma unroll
    for (int r = 0; r < NR; ++r) {
      const int oc = ocg + 32 * r;
      float4 yv;
#pragma unroll
      for (int ff = 0; ff < 4; ++ff) {
        const float cd = tanhf_(accc[r][ff]);
        const float hn = fmaf(uu[r][ff], cd - hreg[r][ff], hreg[r][ff]);
        hreg[r][ff] = hn;
        (&yv.x)[ff] = hn;
      }
      *(float4*)(Y + (size_t)b * yB + (size_t)tl * (HC * 64) + (size_t)oc * 64 + f0) = yv;
      *(float4*)&Hs[oc][f0] = yv;
    }
    __syncthreads();
  }
  __builtin_amdgcn_s_setprio(0);
#pragma unroll
  for (int r = 0; r < NR; ++r) {
    const int oc = ocg + 32 * r;
    *(float4*)(hfinal + ((size_t)b * HC + oc) * 64 + f0) =
        make_float4(hreg[r][0], hreg[r][1], hreg[r][2], hreg[r][3]);
  }
}

struct GruArgs {
  const float* A;
  size_t aB;
  const float* Wgh;
  const float* Wch;
  const float* hinit;
  float* Y;
  size_t yB;
  float* hfinal;
};

template <int HC>
__global__ __launch_bounds__(512) void gru_rec_kernel(GruArgs g) {
  __shared__ float smem[2 * HC * 68];
  gru_body<HC>(smem, g.A, g.aB, g.Wgh, g.Wch, g.hinit, g.Y, g.yB, g.hfinal,
               blockIdx.x);
}

// Heterogeneous gru-only fusion (encoder).
__global__ __launch_bounds__(512) void gru_fused_kernel(GruArgs g64, GruArgs g32) {
  __shared__ float smem[2 * 64 * 68];
  if (blockIdx.x < 64) {
    gru_body<64>(smem, g64.A, g64.aB, g64.Wgh, g64.Wch, g64.hinit, g64.Y,
                 g64.yB, g64.hfinal, blockIdx.x);
  } else {
    gru_body<32>(smem, g32.A, g32.aB, g32.Wgh, g32.Wch, g32.hinit, g32.Y,
                 g32.yB, g32.hfinal, blockIdx.x - 64);
  }
}

// --------------------------------------------------------------------------
// Mega kernel: gru64 + gru32 blocks + conv/final job tiles (2x256 per block).
// kinds: 2 = conv_d0 (INC128), 3 = conv_d1 (INC64), 4 = final.
// --------------------------------------------------------------------------
struct ConvJob {
  int kind;
  int nblk;          // 512-thread blocks = tiles/2
  const float* seq;
  int seqC;
  size_t sB;
  const float* ctx;
  const float* w0;
  const float* w1;
  const float* b0;
  const float* b1;
  float* out;
  int tOff;
};

struct MegaArgs {
  GruArgs g64;
  GruArgs g32;
  int ng64, ng32, njobs;
  ConvJob jobs[4];
};

__global__ __launch_bounds__(512) void mega_kernel(MegaArgs ma) {
  __shared__ float smem[18432];  // max(2*64*68 gru, 2*128*72 conv_d0) floats
  int bid = blockIdx.x;
  if (bid < ma.ng64) {
    gru_body<64>(smem, ma.g64.A, ma.g64.aB, ma.g64.Wgh, ma.g64.Wch,
                 ma.g64.hinit, ma.g64.Y, ma.g64.yB, ma.g64.hfinal, bid);
    return;
  }
  bid -= ma.ng64;
  if (bid < ma.ng32) {
    gru_body<32>(smem, ma.g32.A, ma.g32.aB, ma.g32.Wgh, ma.g32.Wch,
                 ma.g32.hinit, ma.g32.Y, ma.g32.yB, ma.g32.hfinal, bid);
    return;
  }
  bid -= ma.ng32;
  const int half = threadIdx.x >> 8;
  const int tid = threadIdx.x & 255;
#pragma unroll 1
  for (int j = 0; j < ma.njobs; ++j) {
    if (bid < ma.jobs[j].nblk) {
      const ConvJob cj = ma.jobs[j];
      const int tile = bid * 2 + half;
      const int b = tile >> 4;          // tile / TC (TC=16)
      const int tl = tile & (TC - 1);
      if (cj.kind == 2) {
        conv_x_body<128, 128, 64>((float(*)[72])(smem + half * 128 * 72), tid,
                                  b, tl, tile, cj.seq, cj.seqC, cj.sB, cj.ctx,
                                  cj.w0, cj.w1, cj.b0, cj.b1, cj.out);
      } else if (cj.kind == 3) {
        conv_x_body<64, 64, 32>((float(*)[72])(smem + half * 64 * 72), tid,
                                b, tl, tile, cj.seq, cj.seqC, cj.sB, cj.ctx,
                                cj.w0, cj.w1, cj.b0, cj.b1, cj.out);
      } else {
        final_body(tid, tile, cj.seq, cj.w0, cj.b0, cj.out, cj.tOff);
      }
      return;
    }
    bid -= ma.jobs[j].nblk;
  }
}

// --------------------------------------------------------------------------
// Small fp32 GEMM: O[b][e] = sum_k W[e][k]*X[b][k] + bias[e], M=64.
// --------------------------------------------------------------------------
template <bool WT>
__global__ __launch_bounds__(256) void gemm64_kernel(
    const float* __restrict__ W, int wrs,
    const float* __restrict__ X, int xrs,
    float* __restrict__ O, int ors,
    const float* __restrict__ bias, int K,
    int ebh, size_t hsW, size_t hsX, size_t hsO, size_t hsB) {
  int eb = blockIdx.x;
  if (ebh > 0) {
    int h = blockIdx.x / ebh;
    eb = blockIdx.x - h * ebh;
    W += h * hsW; X += h * hsX; O += h * hsO;
    if (bias) bias += h * hsB;
  }
  const int e0 = eb * 64;
  __shared__ float Xs[64][68];
  __shared__ float Ws[64][68];
  const int tb4 = (threadIdx.x & 15) << 2;
  const int te4 = (threadIdx.x >> 4) << 2;
  float acc[4][4] = {};
  for (int k0 = 0; k0 < K; k0 += 64) {
    {
      const int row = threadIdx.x >> 2;
      const int kq = (threadIdx.x & 3) << 4;
      const float* src = X + (size_t)row * xrs + k0 + kq;
#pragma unroll
      for (int q = 0; q < 4; ++q) {
        float4 v = *(const float4*)(src + (q << 2));
        Xs[kq + (q << 2) + 0][row] = v.x;
        Xs[kq + (q << 2) + 1][row] = v.y;
        Xs[kq + (q << 2) + 2][row] = v.z;
        Xs[kq + (q << 2) + 3][row] = v.w;
      }
    }
    if (!WT) {
      const int row = threadIdx.x >> 2;
      const int kq = (threadIdx.x & 3) << 4;
      const float* src = W + (size_t)(e0 + row) * wrs + k0 + kq;
#pragma unroll
      for (int q = 0; q < 4; ++q) {
        float4 v = *(const float4*)(src + (q << 2));
        Ws[kq + (q << 2) + 0][row] = v.x;
        Ws[kq + (q << 2) + 1][row] = v.y;
        Ws[kq + (q << 2) + 2][row] = v.z;
        Ws[kq + (q << 2) + 3][row] = v.w;
      }
    } else {
      const int row = threadIdx.x >> 2;
      const int eq = (threadIdx.x & 3) << 4;
      const float* src = W + (size_t)(k0 + row) * wrs + e0 + eq;
#pragma unroll
      for (int q = 0; q < 4; ++q)
        *(float4*)&Ws[row][eq + (q << 2)] = *(const float4*)(src + (q << 2));
    }
    __syncthreads();
#pragma unroll 8
    for (int k = 0; k < 64; ++k) {
      float4 xv = *(const float4*)&Xs[k][tb4];
      float4 wv4 = *(const float4*)&Ws[k][te4];
      const float xb[4] = {xv.x, xv.y, xv.z, xv.w};
      const float we[4] = {wv4.x, wv4.y, wv4.z, wv4.w};
#pragma unroll
      for (int i = 0; i < 4; ++i)
#pragma unroll
        for (int j = 0; j < 4; ++j) acc[i][j] = fmaf(xb[i], we[j], acc[i][j]);
    }
    __syncthreads();
  }
#pragma unroll
  for (int i = 0; i < 4; ++i)
#pragma unroll
    for (int j = 0; j < 4; ++j) {
      float v = acc[i][j];
      if (bias) v += bias[e0 + te4 + j];
      O[(size_t)(tb4 + i) * ors + e0 + te4 + j] = v;
    }
}

// --------------------------------------------------------------------------
// Attention, parallel form (qlen==1, folded).
// --------------------------------------------------------------------------
__global__ __launch_bounds__(256) void attn_scores_kernel(
    const float* __restrict__ qkh, const float* __restrict__ mem,
    float* __restrict__ scores) {
  const int b = blockIdx.x >> 4;
  const int tt = blockIdx.x & 15;
  const int h = threadIdx.x >> 6;
  const int lane = threadIdx.x & 63;
  const float4* qk4 = (const float4*)(qkh + ((size_t)b * 4 + h) * 4096);
#pragma unroll 2
  for (int ti = 0; ti < 8; ++ti) {
    const int t = tt * 8 + ti;
    const float4* m4 = (const float4*)(mem + ((size_t)b * 128 + t) * 4096);
    float s = 0.f;
    for (int e = lane; e < 1024; e += 64) {
      float4 q = qk4[e], m = m4[e];
      s = fmaf(q.x, m.x, fmaf(q.y, m.y, fmaf(q.z, m.z, fmaf(q.w, m.w, s))));
    }
    s = wsum(s);
    if (lane == 0) scores[((size_t)b * 4 + h) * 128 + t] = s;
  }
}

__global__ __launch_bounds__(256) void attn_softmax_kernel(
    const float* __restrict__ scores, const float* __restrict__ qbuf,
    const float* __restrict__ bqkv, float* __restrict__ attnp) {
  const int b = blockIdx.x;
  const int h = threadIdx.x >> 6;
  const int lane = threadIdx.x & 63;
  const float4* q4 = (const float4*)(qbuf + (size_t)b * 4096 + h * 1024);
  const float4* k4 = (const float4*)(bqkv + 4096 + h * 1024);
  float qb = 0.f;
#pragma unroll
  for (int d = lane; d < 256; d += 64) {
    float4 q = q4[d], k = k4[d];
    qb = fmaf(q.x, k.x, fmaf(q.y, k.y, fmaf(q.z, k.z, fmaf(q.w, k.w, qb))));
  }
  qb = wsum(qb);
  const float* sc = scores + ((size_t)b * 4 + h) * 128;
  float s0 = (sc[lane] + qb) * 0.03125f;
  float s1 = (sc[lane + 64] + qb) * 0.03125f;
  float mx = wmaxr(fmaxf(s0, s1));
  float e0v = __expf(s0 - mx), e1v = __expf(s1 - mx);
  float inv = 1.f / wsum(e0v + e1v);
  attnp[((size_t)b * 4 + h) * 128 + lane] = e0v * inv;
  attnp[((size_t)b * 4 + h) * 128 + lane + 64] = e1v * inv;
}

__global__ __launch_bounds__(256) void attn_wsum_kernel(
    const float* __restrict__ attnp, const float* __restrict__ mem,
    float* __restrict__ wmem) {
  const int b = blockIdx.x >> 4;
  const int eb = blockIdx.x & 15;
  const int e = eb * 256 + threadIdx.x;
  __shared__ float ap[4][128];
  for (int i = threadIdx.x; i < 512; i += 256)
    ap[i >> 7][i & 127] = attnp[(size_t)b * 512 + i];
  __syncthreads();
  float a0 = 0, a1 = 0, a2 = 0, a3 = 0;
  const float* mb = mem + (size_t)b * 128 * 4096 + e;
#pragma unroll 4
  for (int t = 0; t < 128; ++t) {
    float m = mb[(size_t)t * 4096];
    a0 = fmaf(ap[0][t], m, a0);
    a1 = fmaf(ap[1][t], m, a1);
    a2 = fmaf(ap[2][t], m, a2);
    a3 = fmaf(ap[3][t], m, a3);
  }
  wmem[((size_t)b * 4 + 0) * 4096 + e] = a0;
  wmem[((size_t)b * 4 + 1) * 4096 + e] = a1;
  wmem[((size_t)b * 4 + 2) * 4096 + e] = a2;
  wmem[((size_t)b * 4 + 3) * 4096 + e] = a3;
}

// ==========================================================================
extern "C" void kernel_launch(void* const* d_in, const int* in_sizes, int n_in,
                              void* d_out, int out_size, void* d_ws, size_t ws_size,
                              hipStream_t stream) {
  (void)in_sizes; (void)n_in; (void)out_size;
  const float* x     = (const float*)d_in[0];
  const float* wg_e0 = (const float*)d_in[1];
  const float* bg_e0 = (const float*)d_in[2];
  const float* wc_e0 = (const float*)d_in[3];
  const float* bc_e0 = (const float*)d_in[4];
  const float* wg_e1 = (const float*)d_in[5];
  const float* bg_e1 = (const float*)d_in[6];
  const float* wc_e1 = (const float*)d_in[7];
  const float* bc_e1 = (const float*)d_in[8];
  const float* wg_d0 = (const float*)d_in[9];
  const float* bg_d0 = (const float*)d_in[10];
  const float* wc_d0 = (const float*)d_in[11];
  const float* bc_d0 = (const float*)d_in[12];
  const float* wg_d1 = (const float*)d_in[13];
  const float* bg_d1 = (const float*)d_in[14];
  const float* wc_d1 = (const float*)d_in[15];
  const float* bc_d1 = (const float*)d_in[16];
  const float* w_qkv = (const float*)d_in[17];
  const float* b_qkv = (const float*)d_in[18];
  const float* w_out = (const float*)d_in[19];
  const float* b_out = (const float*)d_in[20];
  const float* w_fin = (const float*)d_in[21];
  const float* b_fin = (const float*)d_in[22];
  float* out = (float*)d_out;

  float* WS = (float*)d_ws;
  size_t off = 0;
  auto alloc = [&](size_t n) { float* p = WS + off; off += (n + 63) & ~(size_t)63; return p; };
  float* Amp[2] = {alloc((size_t)B_ * TC * 192 * 64), alloc((size_t)B_ * TC * 192 * 64)};
  float* A96full = alloc((size_t)B_ * T_ * 96 * 64);
  float* A96d[2] = {alloc((size_t)B_ * TC * 96 * 64), alloc((size_t)B_ * TC * 96 * 64)};
  float* Y0p[2] = {alloc((size_t)B_ * TC * 32 * 64), alloc((size_t)B_ * TC * 32 * 64)};
  float* Y1   = alloc((size_t)B_ * T_ * 64 * 64);
  float* Z0p[2] = {alloc((size_t)B_ * TC * 64 * 64), alloc((size_t)B_ * TC * 64 * 64)};
  float* Z1p[2] = {alloc((size_t)B_ * TC * 32 * 64), alloc((size_t)B_ * TC * 32 * 64)};
  float* He0p[2] = {alloc((size_t)B_ * 32 * 64), alloc((size_t)B_ * 32 * 64)};
  float* He1p[2] = {alloc((size_t)B_ * 64 * 64), alloc((size_t)B_ * 64 * 64)};
  float* Hd0p[2] = {alloc((size_t)B_ * 64 * 64), alloc((size_t)B_ * 64 * 64)};
  float* Hd1p[2] = {alloc((size_t)B_ * 32 * 64), alloc((size_t)B_ * 32 * 64)};
  float* QBUF = alloc((size_t)B_ * 4096);
  float* QKH  = alloc((size_t)B_ * 4 * 4096);
  float* WMEM = alloc((size_t)B_ * 4 * 4096);
  float* CTXB = alloc((size_t)B_ * 4096);
  float* CTXO = alloc((size_t)B_ * 4096);
  float* SCR  = alloc((size_t)B_ * 4 * 128);
  float* ATTN = alloc((size_t)B_ * 4 * 128);
  float* wgx_e0 = alloc(64 * 1 * 3);    float* wgh_e0 = alloc(64 * 32 * 3);
  float* wcx_e0 = alloc(32 * 1 * 3);    float* wch_e0 = alloc(32 * 32 * 3);
  float* wgx_e1 = alloc(128 * 32 * 3);  float* wgh_e1 = alloc(128 * 64 * 3);
  float* wcx_e1 = alloc(64 * 32 * 3);   float* wch_e1 = alloc(64 * 64 * 3);
  float* wgx_d0 = alloc(128 * 128 * 3); float* wgh_d0 = alloc(128 * 64 * 3);
  float* wcx_d0 = alloc(64 * 128 * 3);  float* wch_d0 = alloc(64 * 64 * 3);
  float* wgx_d1 = alloc(64 * 64 * 3);   float* wgh_d1 = alloc(64 * 32 * 3);
  float* wcx_d1 = alloc(32 * 64 * 3);   float* wch_d1 = alloc(32 * 32 * 3);
  if (ws_size < off * sizeof(float)) return;

  // Fused weight repack (16 jobs, one launch).
  {
    PackArgs pa;
    const float* srcs[16] = {wg_e0, wg_e0, wc_e0, wc_e0, wg_e1, wg_e1, wc_e1, wc_e1,
                             wg_d0, wg_d0, wc_d0, wc_d0, wg_d1, wg_d1, wc_d1, wc_d1};
    float* dsts[16] = {wgx_e0, wgh_e0, wcx_e0, wch_e0, wgx_e1, wgh_e1, wcx_e1, wch_e1,
                       wgx_d0, wgh_d0, wcx_d0, wch_d0, wgx_d1, wgh_d1, wcx_d1, wch_d1};
    int intot[16] = {33, 33, 33, 33, 96, 96, 96, 96, 192, 192, 192, 192, 96, 96, 96, 96};
    int ic0[16]   = {0, 1, 0, 1, 0, 32, 0, 32, 0, 128, 0, 128, 0, 64, 0, 64};
    int icn[16]   = {1, 32, 1, 32, 32, 64, 32, 64, 128, 64, 128, 64, 64, 32, 64, 32};
    int occ[16]   = {64, 64, 32, 32, 128, 128, 64, 64, 128, 128, 64, 64, 64, 64, 32, 32};
    for (int j = 0; j < 16; ++j) {
      pa.src[j] = srcs[j]; pa.dst[j] = dsts[j];
      pa.intot[j] = intot[j]; pa.ic0[j] = ic0[j]; pa.icn[j] = icn[j]; pa.oc[j] = occ[j];
    }
    pack_all_kernel<<<dim3(192, 16), 256, 0, stream>>>(pa);
  }

  hipMemsetAsync(He0p[0], 0, (size_t)B_ * 32 * 64 * 4, stream);
  hipMemsetAsync(He1p[0], 0, (size_t)B_ * 64 * 64 * 4, stream);

  // -------- encoder --------
  // conv_e0 for ALL chunks in one launch (depends only on x).
  conv_x_kernel<1, 64, 32><<<B_ * T_, 256, 0, stream>>>(
      x, 1, (size_t)T_ * 64, nullptr, wgx_e0, wcx_e0, bg_e0, bc_e0,
      A96full, T_);

  auto g32e = [&](int c) {
    GruArgs g{A96full + (size_t)c * TC * 96 * 64, (size_t)T_ * 96 * 64,
              wgh_e0, wch_e0, He0p[c & 1], Y0p[c & 1], (size_t)TC * 2048,
              He0p[(c + 1) & 1]};
    return g;
  };
  auto conv_e1 = [&](int c) {
    conv_x_kernel<32, 128, 64><<<B_ * TC, 256, 0, stream>>>(
        Y0p[c & 1], 32, (size_t)TC * 2048, nullptr,
        wgx_e1, wcx_e1, bg_e1, bc_e1, Amp[c & 1], TC);
  };

  { GruArgs g = g32e(0); gru_rec_kernel<32><<<64, 512, 0, stream>>>(g); }
  conv_e1(0);
  for (int c = 0; c < NCH; ++c) {
    GruArgs g64 = {Amp[c & 1], (size_t)TC * 192 * 64, wgh_e1, wch_e1,
                   He1p[c & 1], Y1 + (size_t)c * TC * 4096, (size_t)T_ * 4096,
                   He1p[(c + 1) & 1]};
    if (c < NCH - 1) {
      GruArgs g32 = g32e(c + 1);
      gru_fused_kernel<<<128, 512, 0, stream>>>(g64, g32);
      conv_e1(c + 1);
    } else {
      gru_rec_kernel<64><<<64, 512, 0, stream>>>(g64);
    }
  }
  float* He0f = He0p[0];   // NCH even -> final states back in slot 0
  float* He1f = He1p[0];

  // -------- attention (query len 1, folded) --------
  const float* wq = w_qkv;
  const float* wk = w_qkv + (size_t)4096 * 4096;
  const float* wv = w_qkv + (size_t)8192 * 4096;
  gemm64_kernel<false><<<64, 256, 0, stream>>>(wq, 4096, He1f, 4096, QBUF, 4096,
                                               b_qkv, 4096, 0, 0, 0, 0, 0);
  gemm64_kernel<true><<<256, 256, 0, stream>>>(wk, 4096, QBUF, 4096, QKH, 16384,
                                               nullptr, 1024, 64,
                                               (size_t)1024 * 4096, 1024, 4096, 0);
  attn_scores_kernel<<<B_ * 16, 256, 0, stream>>>(QKH, Y1, SCR);
  attn_softmax_kernel<<<B_, 256, 0, stream>>>(SCR, QBUF, b_qkv, ATTN);
  attn_wsum_kernel<<<B_ * 16, 256, 0, stream>>>(ATTN, Y1, WMEM);
  gemm64_kernel<false><<<64, 256, 0, stream>>>(wv, 4096, WMEM, 16384, CTXB, 4096,
                                               b_qkv + 8192, 4096, 16,
                                               (size_t)1024 * 4096, 4096, 1024, 1024);
  gemm64_kernel<false><<<64, 256, 0, stream>>>(w_out, 4096, CTXB, 4096, CTXO, 4096,
                                               b_out, 4096, 0, 0, 0, 0, 0);

  // -------- decoder (10 mega stages; gd0[k] || gd1[k-2]) --------
  auto JD0 = [&](int c, float* dst) {
    ConvJob j{}; j.kind = 2; j.nblk = B_ * TC / 2;
    j.seq = Y1 + (size_t)c * TC * 4096; j.seqC = 64; j.sB = (size_t)T_ * 4096;
    j.ctx = CTXO; j.w0 = wgx_d0; j.w1 = wcx_d0; j.b0 = bg_d0; j.b1 = bc_d0;
    j.out = dst; return j;
  };
  auto JD1 = [&](float* z0src, float* dst) {
    ConvJob j{}; j.kind = 3; j.nblk = B_ * TC / 2;
    j.seq = z0src; j.seqC = 64; j.sB = (size_t)TC * 4096;
    j.ctx = nullptr; j.w0 = wgx_d1; j.w1 = wcx_d1; j.b0 = bg_d1; j.b1 = bc_d1;
    j.out = dst; return j;
  };
  auto JFIN = [&](float* z1src, int tOff) {
    ConvJob j{}; j.kind = 4; j.nblk = B_ * TC * 64 / 512;
    j.seq = z1src; j.w0 = w_fin; j.b0 = b_fin; j.out = out; j.tOff = tOff;
    return j;
  };
  auto mega = [&](const GruArgs* a64, const GruArgs* a32, int nj,
                  const ConvJob* js) {
    MegaArgs ma{};
    ma.ng64 = a64 ? 64 : 0; if (a64) ma.g64 = *a64;
    ma.ng32 = a32 ? 64 : 0; if (a32) ma.g32 = *a32;
    ma.njobs = nj;
    int grid = ma.ng64 + ma.ng32;
    for (int i = 0; i < nj; ++i) { ma.jobs[i] = js[i]; grid += js[i].nblk; }
    mega_kernel<<<grid, 512, 0, stream>>>(ma);
  };

  GruArgs gd0[NCH], gd1[NCH];
  for (int c = 0; c < NCH; ++c) {
    gd0[c] = {Amp[c & 1], (size_t)TC * 192 * 64, wgh_d0, wch_d0,
              (c == 0 ? He1f : Hd0p[c & 1]),
              Z0p[c & 1], (size_t)TC * 4096, Hd0p[(c + 1) & 1]};
    gd1[c] = {A96d[c & 1], (size_t)TC * 96 * 64, wgh_d1, wch_d1,
              (c == 0 ? He0f : Hd1p[c & 1]),
              Z1p[c & 1], (size_t)TC * 2048, Hd1p[(c + 1) & 1]};
  }

  // conv_d0(0) serial (CTXO just computed).
  conv_x_kernel<128, 128, 64><<<B_ * TC, 256, 0, stream>>>(
      Y1, 64, (size_t)T_ * 4096, CTXO, wgx_d0, wcx_d0, bg_d0, bc_d0,
      Amp[0], TC);
  for (int k = 0; k <= NCH + 1; ++k) {
    const GruArgs* a64 = (k <= NCH - 1) ? &gd0[k] : nullptr;
    const GruArgs* a32 = (k >= 2 && k - 2 <= NCH - 1) ? &gd1[k - 2] : nullptr;
    ConvJob js[4];
    int nj = 0;
    if (k + 1 <= NCH - 1) js[nj++] = JD0(k + 1, Amp[(k + 1) & 1]);
    if (k >= 1 && k - 1 <= NCH - 1)
      js[nj++] = JD1(Z0p[(k - 1) & 1], A96d[(k - 1) & 1]);
    if (k >= 3 && k - 3 <= NCH - 1)
      js[nj++] = JFIN(Z1p[(k - 3) & 1], (k - 3) * TC);
    mega(a64, a32, nj, js);
  }
  final_kernel<<<B_ * TC * 64 / 256, 256, 0, stream>>>(
      Z1p[(NCH - 1) & 1], w_fin, b_fin, out, (NCH - 1) * TC);
}